// Round 1
// baseline (486.280 us; speedup 1.0000x reference)
//
#include <hip/hip_runtime.h>
#include <math.h>

#define TT 16
#define BB 32
#define NN 256
#define DD 128
#define NSTEPS 5
#define SKIPF 0.3f
#define EPSF 1e-8f

// Workspace (ws_size = 256 MiB per harness fill): AttA 64 + xb 32 + invn 8 +
// Afin 4 + hT0 2 + hT1 2 + weights ~0.2 = ~112.5 MB.
//
// R7: only outs[-1] is live -> GRU for t<15 is dead code.
// R9: V eliminated; gram computed from staged bf16(x).
// R10 (this round): register-resident gram2. B (64 cols x 128 d bf16) and
// A (32 rows x 128 d, f32) live in VGPRs across the whole h-loop; per-h
// scalars (w^2 f32, invn f32) come from global via L1. LDS pipe -> idle
// (was ~140us of b128 re-reads), A-scaling 4x dedup + cvt_pk (1 op vs 5).

typedef __attribute__((ext_vector_type(8))) short bf16x8;
typedef __attribute__((ext_vector_type(4))) float f32x4;

__device__ __forceinline__ unsigned short f2bf(float f) {
    union { float f; unsigned u; } v; v.f = f;
    unsigned r = (v.u + 0x7FFF + ((v.u >> 16) & 1)) >> 16;
    return (unsigned short)r;
}
__device__ __forceinline__ float bf2f(unsigned short u) {
    union { unsigned u; float f; } v; v.u = ((unsigned)u) << 16; return v.f;
}
__device__ __forceinline__ unsigned pack2(unsigned short a, unsigned short b) {
    return (unsigned)a | ((unsigned)b << 16);
}
__device__ __forceinline__ float lo2f(unsigned u) {
    union { unsigned u; float f; } v; v.u = u << 16; return v.f;
}
__device__ __forceinline__ float hi2f(unsigned u) {
    union { unsigned u; float f; } v; v.u = u & 0xffff0000u; return v.f;
}
// hw packed f32->bf16 convert (RNE), 1 instr for 2 elems (T12 recipe)
__device__ __forceinline__ unsigned cvtpk(float a, float b) {
    unsigned r;
    asm("v_cvt_pk_bf16_f32 %0, %1, %2" : "=v"(r) : "v"(a), "v"(b));
    return r;
}
__device__ __forceinline__ float sigmoidf_(float x) {
    return 1.0f / (1.0f + __expf(-x));
}
__device__ __forceinline__ float tanhf_(float x) {
    return 1.0f - 2.0f / (__expf(2.0f * x) + 1.0f);
}

// ---------------------------------------------------------------------------
// xbf: xb = bf16(x) for ALL 16.7M elements. grid 16384 x 256, 4 elems/thread.
// ---------------------------------------------------------------------------
__global__ __launch_bounds__(256) void k_xbf(const float* __restrict__ x,
                                             unsigned short* __restrict__ xb) {
    size_t idx = ((size_t)blockIdx.x * 256 + threadIdx.x) * 4;
    float4 v = *(const float4*)(x + idx);
    uint2 o;
    o.x = pack2(f2bf(v.x), f2bf(v.y));
    o.y = pack2(f2bf(v.z), f2bf(v.w));
    *(uint2*)(xb + idx) = o;
}

// ---------------------------------------------------------------------------
// norms: invn[tb][h][n] = 1/(sqrt(sum_d x^2 w^2)+eps) for ALL tb in one shot.
// grid = TT*BB*16 blocks (tb, n-group of 16), 256 threads = 16 n x 16 h.
// ---------------------------------------------------------------------------
__global__ __launch_bounds__(256) void k_norms(const float* __restrict__ x,
                                               const float* __restrict__ Wgl,
                                               float* __restrict__ invn) {
    int bid = blockIdx.x;
    int tb = bid >> 4, ng = bid & 15;
    int n0 = ng << 4;
    int tid = threadIdx.x;
    __shared__ float xs[16][132];    // pad 132: 2-way aliasing = free
    __shared__ float ws[16][128];    // w^2, h-row broadcast reads

    {
        int r = tid >> 4, c = (tid & 15) << 3;
        const float* src = x + ((size_t)(tb * 256 + n0 + r) << 7) + c;
        float4 a = *(const float4*)src;
        float4 b = *(const float4*)(src + 4);
        *(float4*)&xs[r][c] = a;
        *(float4*)&xs[r][c + 4] = b;
        const float* wsrc = Wgl + (r << 7) + c;   // r doubles as h
        float4 wa = *(const float4*)wsrc;
        float4 wb = *(const float4*)(wsrc + 4);
        ws[r][c + 0] = wa.x * wa.x; ws[r][c + 1] = wa.y * wa.y;
        ws[r][c + 2] = wa.z * wa.z; ws[r][c + 3] = wa.w * wa.w;
        ws[r][c + 4] = wb.x * wb.x; ws[r][c + 5] = wb.y * wb.y;
        ws[r][c + 6] = wb.z * wb.z; ws[r][c + 7] = wb.w * wb.w;
    }
    __syncthreads();

    int n_l = tid & 15, h = tid >> 4;
    float s = 0.f;
    #pragma unroll
    for (int d = 0; d < 128; d += 4) {
        float4 xv = *(const float4*)&xs[n_l][d];
        float4 wv = *(const float4*)&ws[h][d];
        s = fmaf(xv.x * xv.x, wv.x, s);
        s = fmaf(xv.y * xv.y, wv.y, s);
        s = fmaf(xv.z * xv.z, wv.z, s);
        s = fmaf(xv.w * xv.w, wv.w, s);
    }
    invn[((size_t)(tb * 16 + h) << 8) + n0 + n_l] = 1.0f / (sqrtf(s) + EPSF);
}

// ---------------------------------------------------------------------------
// gram2 (register-resident): attn_t = 0.7*rownorm(relu(sum_h D_h X W2_h X^T D_h)).
// grid = 8 rg x 512 tb = 4096 blocks, 256 threads, LDS = 512 B (rsum only).
// Per wave: B-frags (its 64 cols) resident bf16 (64 VGPR), A-rows (block's
// 32 rows) resident f32 (64 VGPR). Per h: scale A in-reg by f32 w^2 (L1),
// cvt_pk to bf16, 32 MFMAs K=128, epilogue att += invr*invc*g with invn
// read f32 from global (L1). No LDS traffic, no barriers in the h-loop.
// ---------------------------------------------------------------------------
__global__ __launch_bounds__(256, 2) void k_gram2(const unsigned short* __restrict__ xb,
                                                  const float* __restrict__ wsqG,
                                                  const float* __restrict__ invn,
                                                  unsigned short* __restrict__ attn) {
    int bid = blockIdx.x;
    int tb = bid & 511;
    int rg = bid >> 9;                  // 0..7
    int n0 = rg << 5;
    int tid = threadIdx.x;
    int wave = tid >> 6, lane = tid & 63;
    int m16 = lane & 15, quad = lane >> 4;
    int wcol = wave << 6;

    __shared__ float rsum[4][32];

    const unsigned short* Xb = xb + ((size_t)tb << 15);

    // ---- resident B fragments: this wave's 64 cols x 128 d (bf16, raw) ----
    bf16x8 Bf[4][4];                    // [ks][cb] = 64 VGPR
    #pragma unroll
    for (int ks = 0; ks < 4; ++ks)
        #pragma unroll
        for (int cb = 0; cb < 4; ++cb)
            Bf[ks][cb] = *(const bf16x8*)(Xb + ((wcol + (cb << 4) + m16) << 7) + (ks << 5) + (quad << 3));

    // ---- resident A rows, unpacked to f32 once: 32 rows x 128 d ----
    f32x4 Af[2][4][2];                  // [rb][ks][half] = 64 VGPR
    #pragma unroll
    for (int rb = 0; rb < 2; ++rb)
        #pragma unroll
        for (int ks = 0; ks < 4; ++ks) {
            uint4 u = *(const uint4*)(Xb + ((n0 + (rb << 4) + m16) << 7) + (ks << 5) + (quad << 3));
            Af[rb][ks][0] = (f32x4){lo2f(u.x), hi2f(u.x), lo2f(u.y), hi2f(u.y)};
            Af[rb][ks][1] = (f32x4){lo2f(u.z), hi2f(u.z), lo2f(u.w), hi2f(u.w)};
        }

    f32x4 att[2][4];
    #pragma unroll
    for (int rb = 0; rb < 2; ++rb)
        #pragma unroll
        for (int cb = 0; cb < 4; ++cb) att[rb][cb] = (f32x4){0.f, 0.f, 0.f, 0.f};

    const float* ivbase = invn + ((size_t)tb << 12);

    #pragma unroll 1
    for (int h = 0; h < 16; ++h) {
        const float* wh  = wsqG + (h << 7) + (quad << 3);
        const float* ivh = ivbase + (h << 8);

        // epilogue scalars: issue early, independent of the MFMA chain
        f32x4 ivr[2];
        #pragma unroll
        for (int rb = 0; rb < 2; ++rb)
            ivr[rb] = *(const f32x4*)(ivh + n0 + (rb << 4) + (quad << 2));
        float ivc[4];
        #pragma unroll
        for (int cb = 0; cb < 4; ++cb)
            ivc[cb] = ivh[wcol + (cb << 4) + m16];

        f32x4 g[2][4];
        #pragma unroll
        for (int ks = 0; ks < 4; ++ks) {
            f32x4 w0 = *(const f32x4*)(wh + (ks << 5));
            f32x4 w1 = *(const f32x4*)(wh + (ks << 5) + 4);
            bf16x8 afr[2];
            #pragma unroll
            for (int rb = 0; rb < 2; ++rb) {
                f32x4 p0 = Af[rb][ks][0] * w0;
                f32x4 p1 = Af[rb][ks][1] * w1;
                uint4 o;
                o.x = cvtpk(p0[0], p0[1]);
                o.y = cvtpk(p0[2], p0[3]);
                o.z = cvtpk(p1[0], p1[1]);
                o.w = cvtpk(p1[2], p1[3]);
                afr[rb] = *(bf16x8*)&o;
            }
            #pragma unroll
            for (int rb = 0; rb < 2; ++rb)
                #pragma unroll
                for (int cb = 0; cb < 4; ++cb) {
                    f32x4 cin = (ks == 0) ? (f32x4){0.f, 0.f, 0.f, 0.f} : g[rb][cb];
                    g[rb][cb] = __builtin_amdgcn_mfma_f32_16x16x32_bf16(afr[rb], Bf[ks][cb], cin, 0, 0, 0);
                }
        }
        // epilogue: att += invr * invc * g
        #pragma unroll
        for (int rb = 0; rb < 2; ++rb)
            #pragma unroll
            for (int cb = 0; cb < 4; ++cb) {
                float ic = ivc[cb];
                #pragma unroll
                for (int r = 0; r < 4; ++r)
                    att[rb][cb][r] = fmaf(ivr[rb][r] * ic, g[rb][cb][r], att[rb][cb][r]);
            }
    }

    // relu + rowsum + normalize (x0.7) -> bf16 attn  (relu(S)/16 trick: +16eps)
    float rs[2][4];
    #pragma unroll
    for (int rb = 0; rb < 2; ++rb)
        #pragma unroll
        for (int r = 0; r < 4; ++r) {
            float s = 0.f;
            #pragma unroll
            for (int cb = 0; cb < 4; ++cb) {
                float v = fmaxf(att[rb][cb][r], 0.0f);
                att[rb][cb][r] = v;
                s += v;
            }
            rs[rb][r] = s;
        }
    #pragma unroll
    for (int m = 1; m < 16; m <<= 1)
        #pragma unroll
        for (int rb = 0; rb < 2; ++rb)
            #pragma unroll
            for (int r = 0; r < 4; ++r)
                rs[rb][r] += __shfl_xor(rs[rb][r], m, 64);
    if (m16 == 0) {
        #pragma unroll
        for (int rb = 0; rb < 2; ++rb)
            #pragma unroll
            for (int r = 0; r < 4; ++r)
                rsum[wave][(rb << 4) + (quad << 2) + r] = rs[rb][r];
    }
    __syncthreads();

    unsigned short* outb = attn + ((size_t)tb << 16);
    #pragma unroll
    for (int rb = 0; rb < 2; ++rb) {
        #pragma unroll
        for (int r = 0; r < 4; ++r) {
            int row = (rb << 4) + (quad << 2) + r;
            float tot = rsum[0][row] + rsum[1][row] + rsum[2][row] + rsum[3][row];
            float inv = (1.0f - SKIPF) / (tot + 16.0f * EPSF);
            #pragma unroll
            for (int cb = 0; cb < 4; ++cb) {
                int col = (wave << 6) + (cb << 4) + m16;
                outb[((size_t)(n0 + row) << 8) + col] = f2bf(att[rb][cb][r] * inv);
            }
        }
    }
}

// ---------------------------------------------------------------------------
// scanlast: a=supports; a=0.3a+attn_t; write only A_15 (bf16). grid 2048x256.
// ---------------------------------------------------------------------------
__global__ __launch_bounds__(256) void k_scanlast(const float* __restrict__ supports,
                                                  const unsigned short* __restrict__ AttA,
                                                  unsigned short* __restrict__ Afin) {
    size_t flat = ((size_t)blockIdx.x * 256 + threadIdx.x) * 4;
    float4 s4 = *(const float4*)(supports + flat);
    float a0 = s4.x, a1 = s4.y, a2 = s4.z, a3 = s4.w;
    #pragma unroll
    for (int t = 0; t < TT; ++t) {
        const unsigned short* p = AttA + ((size_t)t << 21) + flat;
        uint2 u = *(const uint2*)p;
        a0 = SKIPF * a0 + bf2f((unsigned short)(u.x & 0xffff));
        a1 = SKIPF * a1 + bf2f((unsigned short)(u.x >> 16));
        a2 = SKIPF * a2 + bf2f((unsigned short)(u.y & 0xffff));
        a3 = SKIPF * a3 + bf2f((unsigned short)(u.y >> 16));
    }
    uint2 o;
    o.x = pack2(f2bf(a0), f2bf(a1));
    o.y = pack2(f2bf(a2), f2bf(a3));
    *(uint2*)(Afin + flat) = o;
}

// NOTE: AttA is indexed [tb][n][m] with tb = t*32+b; scanlast's flat index
// covers b,n,m for fixed t via offset t<<21 — consistent with gram2's tb.

// ---------------------------------------------------------------------------
// hTinit: hT0[b][d][n] = bf16(x15[b][n][d]) for b=0..31. grid 32*32 blocks.
// ---------------------------------------------------------------------------
__global__ __launch_bounds__(256) void k_hTinit(const float* __restrict__ x15,
                                                unsigned short* __restrict__ hT) {
    int bid = blockIdx.x;
    int b = bid >> 5; int r = bid & 31; int d0 = (r >> 3) << 5; int n0 = (r & 7) << 5;
    __shared__ float tl[32][33];
    int tid = threadIdx.x;
    int i = tid >> 5, j = tid & 31;
    #pragma unroll
    for (int s = 0; s < 4; ++s) {
        int nl = (s << 3) + i;
        tl[nl][j] = x15[((size_t)(b * 256 + n0 + nl) << 7) + d0 + j];
    }
    __syncthreads();
    #pragma unroll
    for (int s = 0; s < 4; ++s) {
        int dd = (s << 3) + i;
        hT[((size_t)(b * 128 + d0 + dd) << 8) + n0 + j] = f2bf(tl[j][dd]);
    }
}

// ---------------------------------------------------------------------------
// wprep: bf16-transposed weights WT[dout][k] + f32 w^2 table for gram2
// ---------------------------------------------------------------------------
__global__ __launch_bounds__(256) void k_wprep(const float* __restrict__ Wa,
                                               const float* __restrict__ Wr,
                                               const float* __restrict__ Wz,
                                               const float* __restrict__ Wh,
                                               const float* __restrict__ Wgl,
                                               unsigned short* __restrict__ WaT,
                                               unsigned short* __restrict__ WrT,
                                               unsigned short* __restrict__ WzT,
                                               unsigned short* __restrict__ WhT,
                                               float* __restrict__ wsqG) {
    int idx = blockIdx.x * 256 + threadIdx.x;     // 0..32767
    if (idx < 16384) {
        int dout = idx >> 7, din = idx & 127;
        WaT[idx] = f2bf(Wa[(din << 7) + dout]);
    }
    if (idx < 2048) {
        float w = Wgl[idx];
        wsqG[idx] = w * w;
    }
    {
        int dout = idx >> 8, dk = idx & 255;
        WrT[idx] = f2bf(Wr[(dk << 7) + dout]);
        WzT[idx] = f2bf(Wz[(dk << 7) + dout]);
        WhT[idx] = f2bf(Wh[(dk << 7) + dout]);
    }
}

// ---------------------------------------------------------------------------
// step: fused GGNN/GRU step for t=15 only: b = 0..31, 32-row tiles.
// h state in hT (bf16, [b][d][n]). grid = 8 rg x 32 b = 256 blocks.
// ---------------------------------------------------------------------------
__global__ __launch_bounds__(256) void k_step(
    const unsigned short* __restrict__ Afin,
    const unsigned short* __restrict__ hT,
    const unsigned short* __restrict__ WaT, const float* __restrict__ ba,
    const unsigned short* __restrict__ WrT, const float* __restrict__ br,
    const unsigned short* __restrict__ WzT, const float* __restrict__ bz,
    const unsigned short* __restrict__ WhT, const float* __restrict__ bh,
    unsigned short* __restrict__ hT_o) {

    int bid = blockIdx.x;
    int b = bid & 31, rg = bid >> 5;
    int n0 = rg << 5;
    int tid = threadIdx.x;
    int wave = tid >> 6, lane = tid & 63;
    int m16 = lane & 15, quad = lane >> 4;
    int wcol = wave << 5;

    __shared__ unsigned short msgS[32 * 136];
    __shared__ unsigned short ahS[32 * 264];   // k 0..127 = a, 128..255 = h (later r*h)

    const unsigned short* hTb = hT + ((size_t)b << 15);

    // stage h-half of ahS from hT (transpose: ahS[row][128+d] = hT[d][n0+row])
    #pragma unroll
    for (int j = 0; j < 16; ++j) {
        int idx = (j << 8) + tid;            // 0..4095
        int d = idx >> 5, row = idx & 31;
        ahS[row * 264 + 128 + d] = hTb[((size_t)d << 8) + n0 + row];
    }

    // ---- bmm: msg = A_tile @ h  (K=256) ----
    f32x4 acc[2][2];
    #pragma unroll
    for (int rb = 0; rb < 2; ++rb)
        #pragma unroll
        for (int cb = 0; cb < 2; ++cb) acc[rb][cb] = (f32x4){0.f, 0.f, 0.f, 0.f};

    const unsigned short* Ab = Afin + ((size_t)b << 16) + ((size_t)n0 << 8);
    #pragma unroll 2
    for (int ks = 0; ks < 8; ++ks) {
        bf16x8 af[2], bf[2];
        #pragma unroll
        for (int rb = 0; rb < 2; ++rb)
            af[rb] = *(const bf16x8*)(Ab + (((rb << 4) + m16) << 8) + (ks << 5) + (quad << 3));
        #pragma unroll
        for (int cb = 0; cb < 2; ++cb)
            bf[cb] = *(const bf16x8*)(hTb + ((wcol + (cb << 4) + m16) << 8) + (ks << 5) + (quad << 3));
        #pragma unroll
        for (int rb = 0; rb < 2; ++rb)
            #pragma unroll
            for (int cb = 0; cb < 2; ++cb)
                acc[rb][cb] = __builtin_amdgcn_mfma_f32_16x16x32_bf16(af[rb], bf[cb], acc[rb][cb], 0, 0, 0);
    }
    #pragma unroll
    for (int rb = 0; rb < 2; ++rb)
        #pragma unroll
        for (int cb = 0; cb < 2; ++cb)
            #pragma unroll
            for (int r = 0; r < 4; ++r)
                msgS[((rb << 4) + (quad << 2) + r) * 136 + wcol + (cb << 4) + m16] = f2bf(acc[rb][cb][r]);
    __syncthreads();   // covers h-half staging too

    // ---- a = msg @ Wa + ba ----
    #pragma unroll
    for (int rb = 0; rb < 2; ++rb)
        #pragma unroll
        for (int cb = 0; cb < 2; ++cb) acc[rb][cb] = (f32x4){0.f, 0.f, 0.f, 0.f};
    #pragma unroll
    for (int ks = 0; ks < 4; ++ks) {
        bf16x8 af[2], bf[2];
        #pragma unroll
        for (int rb = 0; rb < 2; ++rb)
            af[rb] = *(const bf16x8*)(msgS + ((rb << 4) + m16) * 136 + (ks << 5) + (quad << 3));
        #pragma unroll
        for (int cb = 0; cb < 2; ++cb)
            bf[cb] = *(const bf16x8*)(WaT + ((wcol + (cb << 4) + m16) << 7) + (ks << 5) + (quad << 3));
        #pragma unroll
        for (int rb = 0; rb < 2; ++rb)
            #pragma unroll
            for (int cb = 0; cb < 2; ++cb)
                acc[rb][cb] = __builtin_amdgcn_mfma_f32_16x16x32_bf16(af[rb], bf[cb], acc[rb][cb], 0, 0, 0);
    }
    {
        float bav[2];
        #pragma unroll
        for (int cb = 0; cb < 2; ++cb) bav[cb] = ba[wcol + (cb << 4) + m16];
        #pragma unroll
        for (int rb = 0; rb < 2; ++rb)
            #pragma unroll
            for (int cb = 0; cb < 2; ++cb)
                #pragma unroll
                for (int r = 0; r < 4; ++r)
                    ahS[((rb << 4) + (quad << 2) + r) * 264 + wcol + (cb << 4) + m16] =
                        f2bf(acc[rb][cb][r] + bav[cb]);
    }
    __syncthreads();

    // h_old (for r*h and final update): uint2 = 4 consecutive n at fixed col
    float hv[2][2][4];
    #pragma unroll
    for (int rb = 0; rb < 2; ++rb)
        #pragma unroll
        for (int cb = 0; cb < 2; ++cb) {
            int col = wcol + (cb << 4) + m16;
            uint2 u = *(const uint2*)(hTb + ((size_t)col << 8) + n0 + (rb << 4) + (quad << 2));
            hv[rb][cb][0] = bf2f((unsigned short)(u.x & 0xffff));
            hv[rb][cb][1] = bf2f((unsigned short)(u.x >> 16));
            hv[rb][cb][2] = bf2f((unsigned short)(u.y & 0xffff));
            hv[rb][cb][3] = bf2f((unsigned short)(u.y >> 16));
        }

    // ---- r and z ----
    f32x4 racc[2][2], zacc[2][2];
    #pragma unroll
    for (int rb = 0; rb < 2; ++rb)
        #pragma unroll
        for (int cb = 0; cb < 2; ++cb) {
            racc[rb][cb] = (f32x4){0.f, 0.f, 0.f, 0.f};
            zacc[rb][cb] = (f32x4){0.f, 0.f, 0.f, 0.f};
        }
    #pragma unroll 2
    for (int ks = 0; ks < 8; ++ks) {
        bf16x8 af[2], bfr[2], bfz[2];
        #pragma unroll
        for (int rb = 0; rb < 2; ++rb)
            af[rb] = *(const bf16x8*)(ahS + ((rb << 4) + m16) * 264 + (ks << 5) + (quad << 3));
        #pragma unroll
        for (int cb = 0; cb < 2; ++cb) {
            int dout = wcol + (cb << 4) + m16;
            bfr[cb] = *(const bf16x8*)(WrT + (dout << 8) + (ks << 5) + (quad << 3));
            bfz[cb] = *(const bf16x8*)(WzT + (dout << 8) + (ks << 5) + (quad << 3));
        }
        #pragma unroll
        for (int rb = 0; rb < 2; ++rb)
            #pragma unroll
            for (int cb = 0; cb < 2; ++cb) {
                racc[rb][cb] = __builtin_amdgcn_mfma_f32_16x16x32_bf16(af[rb], bfr[cb], racc[rb][cb], 0, 0, 0);
                zacc[rb][cb] = __builtin_amdgcn_mfma_f32_16x16x32_bf16(af[rb], bfz[cb], zacc[rb][cb], 0, 0, 0);
            }
    }
    float zv[2][2][4];
    {
        float brv[2], bzv[2];
        #pragma unroll
        for (int cb = 0; cb < 2; ++cb) {
            brv[cb] = br[wcol + (cb << 4) + m16];
            bzv[cb] = bz[wcol + (cb << 4) + m16];
        }
        #pragma unroll
        for (int rb = 0; rb < 2; ++rb)
            #pragma unroll
            for (int cb = 0; cb < 2; ++cb)
                #pragma unroll
                for (int r = 0; r < 4; ++r) {
                    racc[rb][cb][r] = sigmoidf_(racc[rb][cb][r] + brv[cb]);
                    zv[rb][cb][r]  = sigmoidf_(zacc[rb][cb][r] + bzv[cb]);
                }
    }
    __syncthreads();   // all ahS reads done -> safe to overwrite h-half

    #pragma unroll
    for (int rb = 0; rb < 2; ++rb)
        #pragma unroll
        for (int cb = 0; cb < 2; ++cb)
            #pragma unroll
            for (int r = 0; r < 4; ++r)
                ahS[((rb << 4) + (quad << 2) + r) * 264 + 128 + wcol + (cb << 4) + m16] =
                    f2bf(racc[rb][cb][r] * hv[rb][cb][r]);
    __syncthreads();

    // ---- h_tilde ----
    #pragma unroll
    for (int rb = 0; rb < 2; ++rb)
        #pragma unroll
        for (int cb = 0; cb < 2; ++cb) acc[rb][cb] = (f32x4){0.f, 0.f, 0.f, 0.f};
    #pragma unroll 2
    for (int ks = 0; ks < 8; ++ks) {
        bf16x8 af[2], bf[2];
        #pragma unroll
        for (int rb = 0; rb < 2; ++rb)
            af[rb] = *(const bf16x8*)(ahS + ((rb << 4) + m16) * 264 + (ks << 5) + (quad << 3));
        #pragma unroll
        for (int cb = 0; cb < 2; ++cb)
            bf[cb] = *(const bf16x8*)(WhT + ((wcol + (cb << 4) + m16) << 8) + (ks << 5) + (quad << 3));
        #pragma unroll
        for (int rb = 0; rb < 2; ++rb)
            #pragma unroll
            for (int cb = 0; cb < 2; ++cb)
                acc[rb][cb] = __builtin_amdgcn_mfma_f32_16x16x32_bf16(af[rb], bf[cb], acc[rb][cb], 0, 0, 0);
    }

    // ---- update + writes (hT only) ----
    {
        float bhv[2];
        #pragma unroll
        for (int cb = 0; cb < 2; ++cb) bhv[cb] = bh[wcol + (cb << 4) + m16];
        #pragma unroll
        for (int rb = 0; rb < 2; ++rb)
            #pragma unroll
            for (int cb = 0; cb < 2; ++cb) {
                int col = wcol + (cb << 4) + m16;
                unsigned short pk[4];
                #pragma unroll
                for (int r = 0; r < 4; ++r) {
                    float ht = tanhf_(acc[rb][cb][r] + bhv[cb]);
                    float hn = hv[rb][cb][r] + zv[rb][cb][r] * (ht - hv[rb][cb][r]);
                    pk[r] = f2bf(hn);
                }
                uint2 p;
                p.x = pack2(pk[0], pk[1]); p.y = pack2(pk[2], pk[3]);
                *(uint2*)(hT_o + ((size_t)(b * 128 + col) << 8) + n0 + (rb << 4) + (quad << 2)) = p;
            }
    }
}

// ---------------------------------------------------------------------------
// fc: logits[b,c] = sum over col-major h (hT1, b slice) + bfc. grid = 512.
// ---------------------------------------------------------------------------
__global__ __launch_bounds__(256) void k_fc(const unsigned short* __restrict__ hT,
                                            const float* __restrict__ Wfc,
                                            const float* __restrict__ bfc,
                                            float* __restrict__ out) {
    int bid = blockIdx.x;
    int b = bid >> 4, part = bid & 15;
    int tid = threadIdx.x;
    const unsigned short* hp = hT + ((size_t)b << 15);
    int i = part * 2048 + tid * 8;       // linear col-major: i = d*256 + n
    int d = i >> 8, n = i & 255;
    uint4 hu = *(const uint4*)(hp + i);
    unsigned short hs[8];
    hs[0] = hu.x & 0xffff; hs[1] = hu.x >> 16;
    hs[2] = hu.y & 0xffff; hs[3] = hu.y >> 16;
    hs[4] = hu.z & 0xffff; hs[5] = hu.z >> 16;
    hs[6] = hu.w & 0xffff; hs[7] = hu.w >> 16;
    float a0 = 0.f, a1 = 0.f;
    #pragma unroll
    for (int k = 0; k < 8; ++k) {
        float v = bf2f(hs[k]);
        const float2 w = *(const float2*)(Wfc + ((size_t)(n + k) * 128 + d) * 2);
        a0 = fmaf(v, w.x, a0);
        a1 = fmaf(v, w.y, a1);
    }
    int wave = tid >> 6, lane = tid & 63;
    #pragma unroll
    for (int off = 32; off; off >>= 1) {
        a0 += __shfl_down(a0, off, 64);
        a1 += __shfl_down(a1, off, 64);
    }
    __shared__ float r0[4], r1[4];
    if (lane == 0) { r0[wave] = a0; r1[wave] = a1; }
    __syncthreads();
    if (tid == 0) {
        float s0 = r0[0] + r0[1] + r0[2] + r0[3];
        float s1 = r1[0] + r1[1] + r1[2] + r1[3];
        if (part == 0) { s0 += bfc[0]; s1 += bfc[1]; }
        atomicAdd(&out[b * 2 + 0], s0);
        atomicAdd(&out[b * 2 + 1], s1);
    }
}

// ---------------------------------------------------------------------------
extern "C" void kernel_launch(void* const* d_in, const int* in_sizes, int n_in,
                              void* d_out, int out_size, void* d_ws, size_t ws_size,
                              hipStream_t stream) {
    const float* x_all    = (const float*)d_in[0];
    const float* supports = (const float*)d_in[1];
    const float* Wgl = (const float*)d_in[2];
    const float* Wa  = (const float*)d_in[3];
    const float* ba  = (const float*)d_in[4];
    const float* Wr  = (const float*)d_in[5];
    const float* br  = (const float*)d_in[6];
    const float* Wz  = (const float*)d_in[7];
    const float* bz  = (const float*)d_in[8];
    const float* Wh  = (const float*)d_in[9];
    const float* bh  = (const float*)d_in[10];
    const float* Wfc = (const float*)d_in[11];
    const float* bfc = (const float*)d_in[12];
    float* out = (float*)d_out;

    char* p = (char*)d_ws;
    auto alloc = [&](size_t bytes) { char* r = p; p += (bytes + 255) & ~(size_t)255; return r; };

    unsigned short* AttA = (unsigned short*)alloc((size_t)TT * BB * NN * NN * 2);  // 64 MB
    unsigned short* xb   = (unsigned short*)alloc((size_t)TT * BB * NN * DD * 2);  // 32 MB
    float* invn          = (float*)alloc((size_t)TT * BB * 16 * NN * 4);           // 8 MB
    unsigned short* Afin = (unsigned short*)alloc((size_t)BB * NN * NN * 2);       // 4 MB
    unsigned short* hT0  = (unsigned short*)alloc((size_t)BB * DD * NN * 2);       // 2 MB
    unsigned short* hT1  = (unsigned short*)alloc((size_t)BB * DD * NN * 2);       // 2 MB
    unsigned short* WaT  = (unsigned short*)alloc(128 * 128 * 2);
    unsigned short* WrT  = (unsigned short*)alloc(256 * 128 * 2);
    unsigned short* WzT  = (unsigned short*)alloc(256 * 128 * 2);
    unsigned short* WhT  = (unsigned short*)alloc(256 * 128 * 2);
    float* wsqG          = (float*)alloc(16 * 128 * 4);                            // 8 KB
    // total ~112.5 MB

    k_wprep<<<128, 256, 0, stream>>>(Wa, Wr, Wz, Wh, Wgl, WaT, WrT, WzT, WhT, wsqG);
    k_xbf<<<16384, 256, 0, stream>>>(x_all, xb);
    k_norms<<<TT * BB * 16, 256, 0, stream>>>(x_all, Wgl, invn);

    // attention path: all 16 t in one dispatch
    k_gram2<<<8 * TT * BB, 256, 0, stream>>>(xb, wsqG, invn, AttA);
    k_scanlast<<<2048, 256, 0, stream>>>(supports, AttA, Afin);

    // GRU path: ONLY t=15 is live (reference uses outs[-1] only)
    const float* x15 = x_all + (size_t)15 * BB * NN * DD;
    k_hTinit<<<BB * 32, 256, 0, stream>>>(x15, hT0);

    const unsigned short* hT_in = hT0;
    for (int s = 0; s < NSTEPS; ++s) {
        unsigned short* hTo = (s & 1) ? hT0 : hT1;
        k_step<<<8 * BB, 256, 0, stream>>>(Afin, hT_in,
                                           WaT, ba, WrT, br, WzT, bz, WhT, bh,
                                           hTo);
        hT_in = hTo;
    }
    // after 5 steps (s=4) final h is in hT1
    hipMemsetAsync(d_out, 0, (size_t)out_size * sizeof(float), stream);
    k_fc<<<BB * 16, 256, 0, stream>>>(hT1, Wfc, bfc, out);
}

// Round 2
// 409.374 us; speedup vs baseline: 1.1879x; 1.1879x over previous
//
#include <hip/hip_runtime.h>
#include <math.h>

#define TT 16
#define BB 32
#define NN 256
#define DD 128
#define NSTEPS 5
#define SKIPF 0.3f
#define EPSF 1e-8f

// Workspace (ws_size = 256 MiB per harness fill): AttA 64 + xb 32 + invn 8 +
// Afin 4 + hT0 2 + hT1 2 + weights ~0.2 = ~112.5 MB.
//
// R7: only outs[-1] is live -> GRU for t<15 is dead code.
// R9: V eliminated; gram computed from staged bf16(x).
// R10: register-resident gram2 (A/B frags live in VGPRs across the h-loop).
//      LDS pipe went idle, VALU halved -- but per-h tables moved to GLOBAL,
//      exposing ~224 L2-latency loads/wave at 2 waves/SIMD => latency-bound.
// R11 (this round): R10 + R9's LDS tables. w^2 (f32) and invn (bf16) staged
//      into LDS once per block; h-loop has ZERO global loads, ~11 conflict-
//      free ds_reads/h. Registers unchanged (~230, 2 waves/SIMD).

typedef __attribute__((ext_vector_type(8))) short bf16x8;
typedef __attribute__((ext_vector_type(4))) float f32x4;

__device__ __forceinline__ unsigned short f2bf(float f) {
    union { float f; unsigned u; } v; v.f = f;
    unsigned r = (v.u + 0x7FFF + ((v.u >> 16) & 1)) >> 16;
    return (unsigned short)r;
}
__device__ __forceinline__ float bf2f(unsigned short u) {
    union { unsigned u; float f; } v; v.u = ((unsigned)u) << 16; return v.f;
}
__device__ __forceinline__ unsigned pack2(unsigned short a, unsigned short b) {
    return (unsigned)a | ((unsigned)b << 16);
}
__device__ __forceinline__ float lo2f(unsigned u) {
    union { unsigned u; float f; } v; v.u = u << 16; return v.f;
}
__device__ __forceinline__ float hi2f(unsigned u) {
    union { unsigned u; float f; } v; v.u = u & 0xffff0000u; return v.f;
}
// hw packed f32->bf16 convert (RNE), 1 instr for 2 elems (T12 recipe)
__device__ __forceinline__ unsigned cvtpk(float a, float b) {
    unsigned r;
    asm("v_cvt_pk_bf16_f32 %0, %1, %2" : "=v"(r) : "v"(a), "v"(b));
    return r;
}
__device__ __forceinline__ float sigmoidf_(float x) {
    return 1.0f / (1.0f + __expf(-x));
}
__device__ __forceinline__ float tanhf_(float x) {
    return 1.0f - 2.0f / (__expf(2.0f * x) + 1.0f);
}

// ---------------------------------------------------------------------------
// xbf: xb = bf16(x) for ALL 16.7M elements. grid 16384 x 256, 4 elems/thread.
// ---------------------------------------------------------------------------
__global__ __launch_bounds__(256) void k_xbf(const float* __restrict__ x,
                                             unsigned short* __restrict__ xb) {
    size_t idx = ((size_t)blockIdx.x * 256 + threadIdx.x) * 4;
    float4 v = *(const float4*)(x + idx);
    uint2 o;
    o.x = pack2(f2bf(v.x), f2bf(v.y));
    o.y = pack2(f2bf(v.z), f2bf(v.w));
    *(uint2*)(xb + idx) = o;
}

// ---------------------------------------------------------------------------
// norms: invn[tb][h][n] = 1/(sqrt(sum_d x^2 w^2)+eps) for ALL tb in one shot.
// grid = TT*BB*16 blocks (tb, n-group of 16), 256 threads = 16 n x 16 h.
// ---------------------------------------------------------------------------
__global__ __launch_bounds__(256) void k_norms(const float* __restrict__ x,
                                               const float* __restrict__ Wgl,
                                               float* __restrict__ invn) {
    int bid = blockIdx.x;
    int tb = bid >> 4, ng = bid & 15;
    int n0 = ng << 4;
    int tid = threadIdx.x;
    __shared__ float xs[16][132];    // pad 132: 2-way aliasing = free
    __shared__ float ws[16][128];    // w^2, h-row broadcast reads

    {
        int r = tid >> 4, c = (tid & 15) << 3;
        const float* src = x + ((size_t)(tb * 256 + n0 + r) << 7) + c;
        float4 a = *(const float4*)src;
        float4 b = *(const float4*)(src + 4);
        *(float4*)&xs[r][c] = a;
        *(float4*)&xs[r][c + 4] = b;
        const float* wsrc = Wgl + (r << 7) + c;   // r doubles as h
        float4 wa = *(const float4*)wsrc;
        float4 wb = *(const float4*)(wsrc + 4);
        ws[r][c + 0] = wa.x * wa.x; ws[r][c + 1] = wa.y * wa.y;
        ws[r][c + 2] = wa.z * wa.z; ws[r][c + 3] = wa.w * wa.w;
        ws[r][c + 4] = wb.x * wb.x; ws[r][c + 5] = wb.y * wb.y;
        ws[r][c + 6] = wb.z * wb.z; ws[r][c + 7] = wb.w * wb.w;
    }
    __syncthreads();

    int n_l = tid & 15, h = tid >> 4;
    float s = 0.f;
    #pragma unroll
    for (int d = 0; d < 128; d += 4) {
        float4 xv = *(const float4*)&xs[n_l][d];
        float4 wv = *(const float4*)&ws[h][d];
        s = fmaf(xv.x * xv.x, wv.x, s);
        s = fmaf(xv.y * xv.y, wv.y, s);
        s = fmaf(xv.z * xv.z, wv.z, s);
        s = fmaf(xv.w * xv.w, wv.w, s);
    }
    invn[((size_t)(tb * 16 + h) << 8) + n0 + n_l] = 1.0f / (sqrtf(s) + EPSF);
}

// ---------------------------------------------------------------------------
// gram2 (register-resident + LDS tables):
//   attn_t = 0.7*rownorm(relu(sum_h D_h X W2_h X^T D_h)).
// grid = 8 rg x 512 tb = 4096 blocks, 256 threads.
// Per wave: B-frags (its 64 cols) resident bf16 (64 VGPR), A-rows (block's
// 32 rows) resident f32 (64 VGPR). Per h: w^2 from LDS (f32), invn from LDS
// (bf16); scale A in-reg, cvt_pk to bf16, 32 MFMAs K=128, epilogue
// att += invr*invc*g. Zero global loads in the h-loop.
// ---------------------------------------------------------------------------
__global__ __launch_bounds__(256, 2) void k_gram2(const unsigned short* __restrict__ xb,
                                                  const float* __restrict__ wsqG,
                                                  const float* __restrict__ invn,
                                                  unsigned short* __restrict__ attn) {
    int bid = blockIdx.x;
    int tb = bid & 511;
    int rg = bid >> 9;                  // 0..7
    int n0 = rg << 5;
    int tid = threadIdx.x;
    int wave = tid >> 6, lane = tid & 63;
    int m16 = lane & 15, quad = lane >> 4;
    int wcol = wave << 6;

    __shared__ float wS[16 * 128];           // 8 KB f32 w^2
    __shared__ unsigned short ivS[16 * 256]; // 8 KB bf16 invn (natural layout)
    __shared__ float rsum[4][32];

    const unsigned short* Xb = xb + ((size_t)tb << 15);

    // ---- stage w^2 (f32) and invn (bf16) into LDS ----
    {
        int c = tid << 3;
        float4 a = *(const float4*)(wsqG + c);
        float4 b = *(const float4*)(wsqG + c + 4);
        *(float4*)(wS + c) = a;
        *(float4*)(wS + c + 4) = b;
    }
    {
        const float* src = invn + ((size_t)tb << 12) + (tid << 4);
        #pragma unroll
        for (int k = 0; k < 4; ++k) {
            float4 v = *(const float4*)(src + (k << 2));
            uint2 o;
            o.x = cvtpk(v.x, v.y);
            o.y = cvtpk(v.z, v.w);
            *(uint2*)(ivS + (tid << 4) + (k << 2)) = o;
        }
    }

    // ---- resident B fragments: this wave's 64 cols x 128 d (bf16, raw) ----
    bf16x8 Bf[4][4];                    // [ks][cb] = 64 VGPR
    #pragma unroll
    for (int ks = 0; ks < 4; ++ks)
        #pragma unroll
        for (int cb = 0; cb < 4; ++cb)
            Bf[ks][cb] = *(const bf16x8*)(Xb + ((wcol + (cb << 4) + m16) << 7) + (ks << 5) + (quad << 3));

    // ---- resident A rows, unpacked to f32 once: 32 rows x 128 d ----
    f32x4 Af[2][4][2];                  // [rb][ks][half] = 64 VGPR
    #pragma unroll
    for (int rb = 0; rb < 2; ++rb)
        #pragma unroll
        for (int ks = 0; ks < 4; ++ks) {
            uint4 u = *(const uint4*)(Xb + ((n0 + (rb << 4) + m16) << 7) + (ks << 5) + (quad << 3));
            Af[rb][ks][0] = (f32x4){lo2f(u.x), hi2f(u.x), lo2f(u.y), hi2f(u.y)};
            Af[rb][ks][1] = (f32x4){lo2f(u.z), hi2f(u.z), lo2f(u.w), hi2f(u.w)};
        }

    f32x4 att[2][4];
    #pragma unroll
    for (int rb = 0; rb < 2; ++rb)
        #pragma unroll
        for (int cb = 0; cb < 4; ++cb) att[rb][cb] = (f32x4){0.f, 0.f, 0.f, 0.f};

    __syncthreads();   // tables staged

    #pragma unroll 1
    for (int h = 0; h < 16; ++h) {
        const float* wh = wS + (h << 7) + (quad << 3);

        // epilogue scalars from LDS (bf16): issue early, independent of MFMA
        float ivr[2][4];
        #pragma unroll
        for (int rb = 0; rb < 2; ++rb) {
            uint2 u = *(const uint2*)(ivS + (h << 8) + n0 + (rb << 4) + (quad << 2));
            ivr[rb][0] = lo2f(u.x); ivr[rb][1] = hi2f(u.x);
            ivr[rb][2] = lo2f(u.y); ivr[rb][3] = hi2f(u.y);
        }
        float ivc[4];
        #pragma unroll
        for (int cb = 0; cb < 4; ++cb)
            ivc[cb] = bf2f(ivS[(h << 8) + wcol + (cb << 4) + m16]);

        f32x4 g[2][4];
        #pragma unroll
        for (int ks = 0; ks < 4; ++ks) {
            f32x4 w0 = *(const f32x4*)(wh + (ks << 5));
            f32x4 w1 = *(const f32x4*)(wh + (ks << 5) + 4);
            bf16x8 afr[2];
            #pragma unroll
            for (int rb = 0; rb < 2; ++rb) {
                f32x4 p0 = Af[rb][ks][0] * w0;
                f32x4 p1 = Af[rb][ks][1] * w1;
                uint4 o;
                o.x = cvtpk(p0[0], p0[1]);
                o.y = cvtpk(p0[2], p0[3]);
                o.z = cvtpk(p1[0], p1[1]);
                o.w = cvtpk(p1[2], p1[3]);
                afr[rb] = *(bf16x8*)&o;
            }
            #pragma unroll
            for (int rb = 0; rb < 2; ++rb)
                #pragma unroll
                for (int cb = 0; cb < 4; ++cb) {
                    f32x4 cin = (ks == 0) ? (f32x4){0.f, 0.f, 0.f, 0.f} : g[rb][cb];
                    g[rb][cb] = __builtin_amdgcn_mfma_f32_16x16x32_bf16(afr[rb], Bf[ks][cb], cin, 0, 0, 0);
                }
        }
        // epilogue: att += invr * invc * g
        #pragma unroll
        for (int rb = 0; rb < 2; ++rb)
            #pragma unroll
            for (int cb = 0; cb < 4; ++cb) {
                float ic = ivc[cb];
                #pragma unroll
                for (int r = 0; r < 4; ++r)
                    att[rb][cb][r] = fmaf(ivr[rb][r] * ic, g[rb][cb][r], att[rb][cb][r]);
            }
    }

    // relu + rowsum + normalize (x0.7) -> bf16 attn  (relu(S)/16 trick: +16eps)
    float rs[2][4];
    #pragma unroll
    for (int rb = 0; rb < 2; ++rb)
        #pragma unroll
        for (int r = 0; r < 4; ++r) {
            float s = 0.f;
            #pragma unroll
            for (int cb = 0; cb < 4; ++cb) {
                float v = fmaxf(att[rb][cb][r], 0.0f);
                att[rb][cb][r] = v;
                s += v;
            }
            rs[rb][r] = s;
        }
    #pragma unroll
    for (int m = 1; m < 16; m <<= 1)
        #pragma unroll
        for (int rb = 0; rb < 2; ++rb)
            #pragma unroll
            for (int r = 0; r < 4; ++r)
                rs[rb][r] += __shfl_xor(rs[rb][r], m, 64);
    if (m16 == 0) {
        #pragma unroll
        for (int rb = 0; rb < 2; ++rb)
            #pragma unroll
            for (int r = 0; r < 4; ++r)
                rsum[wave][(rb << 4) + (quad << 2) + r] = rs[rb][r];
    }
    __syncthreads();

    unsigned short* outb = attn + ((size_t)tb << 16);
    #pragma unroll
    for (int rb = 0; rb < 2; ++rb) {
        #pragma unroll
        for (int r = 0; r < 4; ++r) {
            int row = (rb << 4) + (quad << 2) + r;
            float tot = rsum[0][row] + rsum[1][row] + rsum[2][row] + rsum[3][row];
            float inv = (1.0f - SKIPF) / (tot + 16.0f * EPSF);
            #pragma unroll
            for (int cb = 0; cb < 4; ++cb) {
                int col = (wave << 6) + (cb << 4) + m16;
                outb[((size_t)(n0 + row) << 8) + col] = f2bf(att[rb][cb][r] * inv);
            }
        }
    }
}

// ---------------------------------------------------------------------------
// scanlast: a=supports; a=0.3a+attn_t; write only A_15 (bf16). grid 2048x256.
// ---------------------------------------------------------------------------
__global__ __launch_bounds__(256) void k_scanlast(const float* __restrict__ supports,
                                                  const unsigned short* __restrict__ AttA,
                                                  unsigned short* __restrict__ Afin) {
    size_t flat = ((size_t)blockIdx.x * 256 + threadIdx.x) * 4;
    float4 s4 = *(const float4*)(supports + flat);
    float a0 = s4.x, a1 = s4.y, a2 = s4.z, a3 = s4.w;
    #pragma unroll
    for (int t = 0; t < TT; ++t) {
        const unsigned short* p = AttA + ((size_t)t << 21) + flat;
        uint2 u = *(const uint2*)p;
        a0 = SKIPF * a0 + bf2f((unsigned short)(u.x & 0xffff));
        a1 = SKIPF * a1 + bf2f((unsigned short)(u.x >> 16));
        a2 = SKIPF * a2 + bf2f((unsigned short)(u.y & 0xffff));
        a3 = SKIPF * a3 + bf2f((unsigned short)(u.y >> 16));
    }
    uint2 o;
    o.x = pack2(f2bf(a0), f2bf(a1));
    o.y = pack2(f2bf(a2), f2bf(a3));
    *(uint2*)(Afin + flat) = o;
}

// NOTE: AttA is indexed [tb][n][m] with tb = t*32+b; scanlast's flat index
// covers b,n,m for fixed t via offset t<<21 — consistent with gram2's tb.

// ---------------------------------------------------------------------------
// hTinit: hT0[b][d][n] = bf16(x15[b][n][d]) for b=0..31. grid 32*32 blocks.
// ---------------------------------------------------------------------------
__global__ __launch_bounds__(256) void k_hTinit(const float* __restrict__ x15,
                                                unsigned short* __restrict__ hT) {
    int bid = blockIdx.x;
    int b = bid >> 5; int r = bid & 31; int d0 = (r >> 3) << 5; int n0 = (r & 7) << 5;
    __shared__ float tl[32][33];
    int tid = threadIdx.x;
    int i = tid >> 5, j = tid & 31;
    #pragma unroll
    for (int s = 0; s < 4; ++s) {
        int nl = (s << 3) + i;
        tl[nl][j] = x15[((size_t)(b * 256 + n0 + nl) << 7) + d0 + j];
    }
    __syncthreads();
    #pragma unroll
    for (int s = 0; s < 4; ++s) {
        int dd = (s << 3) + i;
        hT[((size_t)(b * 128 + d0 + dd) << 8) + n0 + j] = f2bf(tl[j][dd]);
    }
}

// ---------------------------------------------------------------------------
// wprep: bf16-transposed weights WT[dout][k] + f32 w^2 table for gram2
// ---------------------------------------------------------------------------
__global__ __launch_bounds__(256) void k_wprep(const float* __restrict__ Wa,
                                               const float* __restrict__ Wr,
                                               const float* __restrict__ Wz,
                                               const float* __restrict__ Wh,
                                               const float* __restrict__ Wgl,
                                               unsigned short* __restrict__ WaT,
                                               unsigned short* __restrict__ WrT,
                                               unsigned short* __restrict__ WzT,
                                               unsigned short* __restrict__ WhT,
                                               float* __restrict__ wsqG) {
    int idx = blockIdx.x * 256 + threadIdx.x;     // 0..32767
    if (idx < 16384) {
        int dout = idx >> 7, din = idx & 127;
        WaT[idx] = f2bf(Wa[(din << 7) + dout]);
    }
    if (idx < 2048) {
        float w = Wgl[idx];
        wsqG[idx] = w * w;
    }
    {
        int dout = idx >> 8, dk = idx & 255;
        WrT[idx] = f2bf(Wr[(dk << 7) + dout]);
        WzT[idx] = f2bf(Wz[(dk << 7) + dout]);
        WhT[idx] = f2bf(Wh[(dk << 7) + dout]);
    }
}

// ---------------------------------------------------------------------------
// step: fused GGNN/GRU step for t=15 only: b = 0..31, 32-row tiles.
// h state in hT (bf16, [b][d][n]). grid = 8 rg x 32 b = 256 blocks.
// ---------------------------------------------------------------------------
__global__ __launch_bounds__(256) void k_step(
    const unsigned short* __restrict__ Afin,
    const unsigned short* __restrict__ hT,
    const unsigned short* __restrict__ WaT, const float* __restrict__ ba,
    const unsigned short* __restrict__ WrT, const float* __restrict__ br,
    const unsigned short* __restrict__ WzT, const float* __restrict__ bz,
    const unsigned short* __restrict__ WhT, const float* __restrict__ bh,
    unsigned short* __restrict__ hT_o) {

    int bid = blockIdx.x;
    int b = bid & 31, rg = bid >> 5;
    int n0 = rg << 5;
    int tid = threadIdx.x;
    int wave = tid >> 6, lane = tid & 63;
    int m16 = lane & 15, quad = lane >> 4;
    int wcol = wave << 5;

    __shared__ unsigned short msgS[32 * 136];
    __shared__ unsigned short ahS[32 * 264];   // k 0..127 = a, 128..255 = h (later r*h)

    const unsigned short* hTb = hT + ((size_t)b << 15);

    // stage h-half of ahS from hT (transpose: ahS[row][128+d] = hT[d][n0+row])
    #pragma unroll
    for (int j = 0; j < 16; ++j) {
        int idx = (j << 8) + tid;            // 0..4095
        int d = idx >> 5, row = idx & 31;
        ahS[row * 264 + 128 + d] = hTb[((size_t)d << 8) + n0 + row];
    }

    // ---- bmm: msg = A_tile @ h  (K=256) ----
    f32x4 acc[2][2];
    #pragma unroll
    for (int rb = 0; rb < 2; ++rb)
        #pragma unroll
        for (int cb = 0; cb < 2; ++cb) acc[rb][cb] = (f32x4){0.f, 0.f, 0.f, 0.f};

    const unsigned short* Ab = Afin + ((size_t)b << 16) + ((size_t)n0 << 8);
    #pragma unroll 2
    for (int ks = 0; ks < 8; ++ks) {
        bf16x8 af[2], bf[2];
        #pragma unroll
        for (int rb = 0; rb < 2; ++rb)
            af[rb] = *(const bf16x8*)(Ab + (((rb << 4) + m16) << 8) + (ks << 5) + (quad << 3));
        #pragma unroll
        for (int cb = 0; cb < 2; ++cb)
            bf[cb] = *(const bf16x8*)(hTb + ((wcol + (cb << 4) + m16) << 8) + (ks << 5) + (quad << 3));
        #pragma unroll
        for (int rb = 0; rb < 2; ++rb)
            #pragma unroll
            for (int cb = 0; cb < 2; ++cb)
                acc[rb][cb] = __builtin_amdgcn_mfma_f32_16x16x32_bf16(af[rb], bf[cb], acc[rb][cb], 0, 0, 0);
    }
    #pragma unroll
    for (int rb = 0; rb < 2; ++rb)
        #pragma unroll
        for (int cb = 0; cb < 2; ++cb)
            #pragma unroll
            for (int r = 0; r < 4; ++r)
                msgS[((rb << 4) + (quad << 2) + r) * 136 + wcol + (cb << 4) + m16] = f2bf(acc[rb][cb][r]);
    __syncthreads();   // covers h-half staging too

    // ---- a = msg @ Wa + ba ----
    #pragma unroll
    for (int rb = 0; rb < 2; ++rb)
        #pragma unroll
        for (int cb = 0; cb < 2; ++cb) acc[rb][cb] = (f32x4){0.f, 0.f, 0.f, 0.f};
    #pragma unroll
    for (int ks = 0; ks < 4; ++ks) {
        bf16x8 af[2], bf[2];
        #pragma unroll
        for (int rb = 0; rb < 2; ++rb)
            af[rb] = *(const bf16x8*)(msgS + ((rb << 4) + m16) * 136 + (ks << 5) + (quad << 3));
        #pragma unroll
        for (int cb = 0; cb < 2; ++cb)
            bf[cb] = *(const bf16x8*)(WaT + ((wcol + (cb << 4) + m16) << 7) + (ks << 5) + (quad << 3));
        #pragma unroll
        for (int rb = 0; rb < 2; ++rb)
            #pragma unroll
            for (int cb = 0; cb < 2; ++cb)
                acc[rb][cb] = __builtin_amdgcn_mfma_f32_16x16x32_bf16(af[rb], bf[cb], acc[rb][cb], 0, 0, 0);
    }
    {
        float bav[2];
        #pragma unroll
        for (int cb = 0; cb < 2; ++cb) bav[cb] = ba[wcol + (cb << 4) + m16];
        #pragma unroll
        for (int rb = 0; rb < 2; ++rb)
            #pragma unroll
            for (int cb = 0; cb < 2; ++cb)
                #pragma unroll
                for (int r = 0; r < 4; ++r)
                    ahS[((rb << 4) + (quad << 2) + r) * 264 + wcol + (cb << 4) + m16] =
                        f2bf(acc[rb][cb][r] + bav[cb]);
    }
    __syncthreads();

    // h_old (for r*h and final update): uint2 = 4 consecutive n at fixed col
    float hv[2][2][4];
    #pragma unroll
    for (int rb = 0; rb < 2; ++rb)
        #pragma unroll
        for (int cb = 0; cb < 2; ++cb) {
            int col = wcol + (cb << 4) + m16;
            uint2 u = *(const uint2*)(hTb + ((size_t)col << 8) + n0 + (rb << 4) + (quad << 2));
            hv[rb][cb][0] = bf2f((unsigned short)(u.x & 0xffff));
            hv[rb][cb][1] = bf2f((unsigned short)(u.x >> 16));
            hv[rb][cb][2] = bf2f((unsigned short)(u.y & 0xffff));
            hv[rb][cb][3] = bf2f((unsigned short)(u.y >> 16));
        }

    // ---- r and z ----
    f32x4 racc[2][2], zacc[2][2];
    #pragma unroll
    for (int rb = 0; rb < 2; ++rb)
        #pragma unroll
        for (int cb = 0; cb < 2; ++cb) {
            racc[rb][cb] = (f32x4){0.f, 0.f, 0.f, 0.f};
            zacc[rb][cb] = (f32x4){0.f, 0.f, 0.f, 0.f};
        }
    #pragma unroll 2
    for (int ks = 0; ks < 8; ++ks) {
        bf16x8 af[2], bfr[2], bfz[2];
        #pragma unroll
        for (int rb = 0; rb < 2; ++rb)
            af[rb] = *(const bf16x8*)(ahS + ((rb << 4) + m16) * 264 + (ks << 5) + (quad << 3));
        #pragma unroll
        for (int cb = 0; cb < 2; ++cb) {
            int dout = wcol + (cb << 4) + m16;
            bfr[cb] = *(const bf16x8*)(WrT + (dout << 8) + (ks << 5) + (quad << 3));
            bfz[cb] = *(const bf16x8*)(WzT + (dout << 8) + (ks << 5) + (quad << 3));
        }
        #pragma unroll
        for (int rb = 0; rb < 2; ++rb)
            #pragma unroll
            for (int cb = 0; cb < 2; ++cb) {
                racc[rb][cb] = __builtin_amdgcn_mfma_f32_16x16x32_bf16(af[rb], bfr[cb], racc[rb][cb], 0, 0, 0);
                zacc[rb][cb] = __builtin_amdgcn_mfma_f32_16x16x32_bf16(af[rb], bfz[cb], zacc[rb][cb], 0, 0, 0);
            }
    }
    float zv[2][2][4];
    {
        float brv[2], bzv[2];
        #pragma unroll
        for (int cb = 0; cb < 2; ++cb) {
            brv[cb] = br[wcol + (cb << 4) + m16];
            bzv[cb] = bz[wcol + (cb << 4) + m16];
        }
        #pragma unroll
        for (int rb = 0; rb < 2; ++rb)
            #pragma unroll
            for (int cb = 0; cb < 2; ++cb)
                #pragma unroll
                for (int r = 0; r < 4; ++r) {
                    racc[rb][cb][r] = sigmoidf_(racc[rb][cb][r] + brv[cb]);
                    zv[rb][cb][r]  = sigmoidf_(zacc[rb][cb][r] + bzv[cb]);
                }
    }
    __syncthreads();   // all ahS reads done -> safe to overwrite h-half

    #pragma unroll
    for (int rb = 0; rb < 2; ++rb)
        #pragma unroll
        for (int cb = 0; cb < 2; ++cb)
            #pragma unroll
            for (int r = 0; r < 4; ++r)
                ahS[((rb << 4) + (quad << 2) + r) * 264 + 128 + wcol + (cb << 4) + m16] =
                    f2bf(racc[rb][cb][r] * hv[rb][cb][r]);
    __syncthreads();

    // ---- h_tilde ----
    #pragma unroll
    for (int rb = 0; rb < 2; ++rb)
        #pragma unroll
        for (int cb = 0; cb < 2; ++cb) acc[rb][cb] = (f32x4){0.f, 0.f, 0.f, 0.f};
    #pragma unroll 2
    for (int ks = 0; ks < 8; ++ks) {
        bf16x8 af[2], bf[2];
        #pragma unroll
        for (int rb = 0; rb < 2; ++rb)
            af[rb] = *(const bf16x8*)(ahS + ((rb << 4) + m16) * 264 + (ks << 5) + (quad << 3));
        #pragma unroll
        for (int cb = 0; cb < 2; ++cb)
            bf[cb] = *(const bf16x8*)(WhT + ((wcol + (cb << 4) + m16) << 8) + (ks << 5) + (quad << 3));
        #pragma unroll
        for (int rb = 0; rb < 2; ++rb)
            #pragma unroll
            for (int cb = 0; cb < 2; ++cb)
                acc[rb][cb] = __builtin_amdgcn_mfma_f32_16x16x32_bf16(af[rb], bf[cb], acc[rb][cb], 0, 0, 0);
    }

    // ---- update + writes (hT only) ----
    {
        float bhv[2];
        #pragma unroll
        for (int cb = 0; cb < 2; ++cb) bhv[cb] = bh[wcol + (cb << 4) + m16];
        #pragma unroll
        for (int rb = 0; rb < 2; ++rb)
            #pragma unroll
            for (int cb = 0; cb < 2; ++cb) {
                int col = wcol + (cb << 4) + m16;
                unsigned short pk[4];
                #pragma unroll
                for (int r = 0; r < 4; ++r) {
                    float ht = tanhf_(acc[rb][cb][r] + bhv[cb]);
                    float hn = hv[rb][cb][r] + zv[rb][cb][r] * (ht - hv[rb][cb][r]);
                    pk[r] = f2bf(hn);
                }
                uint2 p;
                p.x = pack2(pk[0], pk[1]); p.y = pack2(pk[2], pk[3]);
                *(uint2*)(hT_o + ((size_t)(b * 128 + col) << 8) + n0 + (rb << 4) + (quad << 2)) = p;
            }
    }
}

// ---------------------------------------------------------------------------
// fc: logits[b,c] = sum over col-major h (hT1, b slice) + bfc. grid = 512.
// ---------------------------------------------------------------------------
__global__ __launch_bounds__(256) void k_fc(const unsigned short* __restrict__ hT,
                                            const float* __restrict__ Wfc,
                                            const float* __restrict__ bfc,
                                            float* __restrict__ out) {
    int bid = blockIdx.x;
    int b = bid >> 4, part = bid & 15;
    int tid = threadIdx.x;
    const unsigned short* hp = hT + ((size_t)b << 15);
    int i = part * 2048 + tid * 8;       // linear col-major: i = d*256 + n
    int d = i >> 8, n = i & 255;
    uint4 hu = *(const uint4*)(hp + i);
    unsigned short hs[8];
    hs[0] = hu.x & 0xffff; hs[1] = hu.x >> 16;
    hs[2] = hu.y & 0xffff; hs[3] = hu.y >> 16;
    hs[4] = hu.z & 0xffff; hs[5] = hu.z >> 16;
    hs[6] = hu.w & 0xffff; hs[7] = hu.w >> 16;
    float a0 = 0.f, a1 = 0.f;
    #pragma unroll
    for (int k = 0; k < 8; ++k) {
        float v = bf2f(hs[k]);
        const float2 w = *(const float2*)(Wfc + ((size_t)(n + k) * 128 + d) * 2);
        a0 = fmaf(v, w.x, a0);
        a1 = fmaf(v, w.y, a1);
    }
    int wave = tid >> 6, lane = tid & 63;
    #pragma unroll
    for (int off = 32; off; off >>= 1) {
        a0 += __shfl_down(a0, off, 64);
        a1 += __shfl_down(a1, off, 64);
    }
    __shared__ float r0[4], r1[4];
    if (lane == 0) { r0[wave] = a0; r1[wave] = a1; }
    __syncthreads();
    if (tid == 0) {
        float s0 = r0[0] + r0[1] + r0[2] + r0[3];
        float s1 = r1[0] + r1[1] + r1[2] + r1[3];
        if (part == 0) { s0 += bfc[0]; s1 += bfc[1]; }
        atomicAdd(&out[b * 2 + 0], s0);
        atomicAdd(&out[b * 2 + 1], s1);
    }
}

// ---------------------------------------------------------------------------
extern "C" void kernel_launch(void* const* d_in, const int* in_sizes, int n_in,
                              void* d_out, int out_size, void* d_ws, size_t ws_size,
                              hipStream_t stream) {
    const float* x_all    = (const float*)d_in[0];
    const float* supports = (const float*)d_in[1];
    const float* Wgl = (const float*)d_in[2];
    const float* Wa  = (const float*)d_in[3];
    const float* ba  = (const float*)d_in[4];
    const float* Wr  = (const float*)d_in[5];
    const float* br  = (const float*)d_in[6];
    const float* Wz  = (const float*)d_in[7];
    const float* bz  = (const float*)d_in[8];
    const float* Wh  = (const float*)d_in[9];
    const float* bh  = (const float*)d_in[10];
    const float* Wfc = (const float*)d_in[11];
    const float* bfc = (const float*)d_in[12];
    float* out = (float*)d_out;

    char* p = (char*)d_ws;
    auto alloc = [&](size_t bytes) { char* r = p; p += (bytes + 255) & ~(size_t)255; return r; };

    unsigned short* AttA = (unsigned short*)alloc((size_t)TT * BB * NN * NN * 2);  // 64 MB
    unsigned short* xb   = (unsigned short*)alloc((size_t)TT * BB * NN * DD * 2);  // 32 MB
    float* invn          = (float*)alloc((size_t)TT * BB * 16 * NN * 4);           // 8 MB
    unsigned short* Afin = (unsigned short*)alloc((size_t)BB * NN * NN * 2);       // 4 MB
    unsigned short* hT0  = (unsigned short*)alloc((size_t)BB * DD * NN * 2);       // 2 MB
    unsigned short* hT1  = (unsigned short*)alloc((size_t)BB * DD * NN * 2);       // 2 MB
    unsigned short* WaT  = (unsigned short*)alloc(128 * 128 * 2);
    unsigned short* WrT  = (unsigned short*)alloc(256 * 128 * 2);
    unsigned short* WzT  = (unsigned short*)alloc(256 * 128 * 2);
    unsigned short* WhT  = (unsigned short*)alloc(256 * 128 * 2);
    float* wsqG          = (float*)alloc(16 * 128 * 4);                            // 8 KB
    // total ~112.5 MB

    k_wprep<<<128, 256, 0, stream>>>(Wa, Wr, Wz, Wh, Wgl, WaT, WrT, WzT, WhT, wsqG);
    k_xbf<<<16384, 256, 0, stream>>>(x_all, xb);
    k_norms<<<TT * BB * 16, 256, 0, stream>>>(x_all, Wgl, invn);

    // attention path: all 16 t in one dispatch
    k_gram2<<<8 * TT * BB, 256, 0, stream>>>(xb, wsqG, invn, AttA);
    k_scanlast<<<2048, 256, 0, stream>>>(supports, AttA, Afin);

    // GRU path: ONLY t=15 is live (reference uses outs[-1] only)
    const float* x15 = x_all + (size_t)15 * BB * NN * DD;
    k_hTinit<<<BB * 32, 256, 0, stream>>>(x15, hT0);

    const unsigned short* hT_in = hT0;
    for (int s = 0; s < NSTEPS; ++s) {
        unsigned short* hTo = (s & 1) ? hT0 : hT1;
        k_step<<<8 * BB, 256, 0, stream>>>(Afin, hT_in,
                                           WaT, ba, WrT, br, WzT, bz, WhT, bh,
                                           hTo);
        hT_in = hTo;
    }
    // after 5 steps (s=4) final h is in hT1
    hipMemsetAsync(d_out, 0, (size_t)out_size * sizeof(float), stream);
    k_fc<<<BB * 16, 256, 0, stream>>>(hT1, Wfc, bfc, out);
}

// Round 3
// 385.451 us; speedup vs baseline: 1.2616x; 1.0621x over previous
//
#include <hip/hip_runtime.h>
#include <math.h>

#define TT 16
#define BB 32
#define NN 256
#define DD 128
#define NSTEPS 5
#define SKIPF 0.3f
#define EPSF 1e-8f

// Workspace (ws_size = 256 MiB per harness fill): AttA 64 + xh 32 + invnH 8 +
// Afin 4 + hT0 2 + hT1 2 + weights ~0.2 = ~112.5 MB.
//
// R7: only outs[-1] is live -> GRU for t<15 is dead code.
// R9: V eliminated; gram computed from staged low-precision x.
// R10: register-resident gram2 (A/B frags live in VGPRs across the h-loop).
// R11: LDS tables for w^2/invn -> issue-saturated (VALU 55 + MFMA 36 = 91%).
// R12 (this round): f16 packed-math gram. x stored f16; A/B resident PACKED;
//      per-h scaling via v_pk_mul_f16 (A gets w^2*invr, B gets invc); MFMA
//      f16 accumulates att directly across all h (no per-h g, no f32
//      epilogue). xbf fused into norms (x read once). ~45% VALU-issue cut.

typedef __attribute__((ext_vector_type(8))) short bf16x8;
typedef __attribute__((ext_vector_type(4))) float f32x4;
typedef __attribute__((ext_vector_type(8))) _Float16 half8;
typedef __attribute__((ext_vector_type(2))) _Float16 h2;

__device__ __forceinline__ unsigned short f2bf(float f) {
    union { float f; unsigned u; } v; v.f = f;
    unsigned r = (v.u + 0x7FFF + ((v.u >> 16) & 1)) >> 16;
    return (unsigned short)r;
}
__device__ __forceinline__ float bf2f(unsigned short u) {
    union { unsigned u; float f; } v; v.u = ((unsigned)u) << 16; return v.f;
}
__device__ __forceinline__ unsigned pack2(unsigned short a, unsigned short b) {
    return (unsigned)a | ((unsigned)b << 16);
}
// packed f32->f16 convert (RTZ), 1 inst for 2 elems
__device__ __forceinline__ unsigned pkrtz(float a, float b) {
    unsigned r;
    asm("v_cvt_pkrtz_f16_f32 %0, %1, %2" : "=v"(r) : "v"(a), "v"(b));
    return r;
}
__device__ __forceinline__ h2 u2h(unsigned u) {
    union { unsigned u; h2 h; } v; v.u = u; return v.h;
}
__device__ __forceinline__ float sigmoidf_(float x) {
    return 1.0f / (1.0f + __expf(-x));
}
__device__ __forceinline__ float tanhf_(float x) {
    return 1.0f - 2.0f / (__expf(2.0f * x) + 1.0f);
}

// ---------------------------------------------------------------------------
// norms (fused with xbf): per block (tb, 16-row group):
//   xh = f16(x) written out (32 MB total)
//   invnH[tb][h][n] = dup-f16( 1/(sqrt(sum_d x^2 w^2)+eps) )
// grid = TT*BB*16 blocks, 256 threads = 16 n x 16 h.
// ---------------------------------------------------------------------------
__global__ __launch_bounds__(256) void k_norms(const float* __restrict__ x,
                                               const float* __restrict__ Wgl,
                                               unsigned short* __restrict__ xh,
                                               unsigned* __restrict__ invnH) {
    int bid = blockIdx.x;
    int tb = bid >> 4, ng = bid & 15;
    int n0 = ng << 4;
    int tid = threadIdx.x;
    __shared__ float xs[16][132];    // pad 132: 2-way aliasing = free
    __shared__ float ws[16][128];    // w^2, h-row broadcast reads

    {
        int r = tid >> 4, c = (tid & 15) << 3;
        const float* src = x + ((size_t)(tb * 256 + n0 + r) << 7) + c;
        float4 a = *(const float4*)src;
        float4 b = *(const float4*)(src + 4);
        *(float4*)&xs[r][c] = a;
        *(float4*)&xs[r][c + 4] = b;
        // f16 conversion of the same 8 values -> xh
        uint4 o;
        o.x = pkrtz(a.x, a.y); o.y = pkrtz(a.z, a.w);
        o.z = pkrtz(b.x, b.y); o.w = pkrtz(b.z, b.w);
        *(uint4*)(xh + ((size_t)(tb * 256 + n0 + r) << 7) + c) = o;
        const float* wsrc = Wgl + (r << 7) + c;   // r doubles as h
        float4 wa = *(const float4*)wsrc;
        float4 wb = *(const float4*)(wsrc + 4);
        ws[r][c + 0] = wa.x * wa.x; ws[r][c + 1] = wa.y * wa.y;
        ws[r][c + 2] = wa.z * wa.z; ws[r][c + 3] = wa.w * wa.w;
        ws[r][c + 4] = wb.x * wb.x; ws[r][c + 5] = wb.y * wb.y;
        ws[r][c + 6] = wb.z * wb.z; ws[r][c + 7] = wb.w * wb.w;
    }
    __syncthreads();

    int n_l = tid & 15, h = tid >> 4;
    float s = 0.f;
    #pragma unroll
    for (int d = 0; d < 128; d += 4) {
        float4 xv = *(const float4*)&xs[n_l][d];
        float4 wv = *(const float4*)&ws[h][d];
        s = fmaf(xv.x * xv.x, wv.x, s);
        s = fmaf(xv.y * xv.y, wv.y, s);
        s = fmaf(xv.z * xv.z, wv.z, s);
        s = fmaf(xv.w * xv.w, wv.w, s);
    }
    float inv = 1.0f / (sqrtf(s) + EPSF);
    invnH[((size_t)(tb * 16 + h) << 8) + n0 + n_l] = pkrtz(inv, inv);
}

// ---------------------------------------------------------------------------
// gram2 (f16 packed, all scaling in fragments):
//   attn_t = 0.7*rownorm(relu(sum_h D_h X W2_h X^T D_h)).
// grid = 8 rg x 512 tb = 4096 blocks, 256 threads, LDS 20.5 KB.
// Per wave: B raw f16 (its 64 cols, 64 VGPR packed), A raw f16 (block's 32
// rows, 32 VGPR packed). Per h: A-frag = A*(w^2*invr) [8 pk_mul/frag],
// B-frag = B*invc [4 pk_mul/frag]; MFMA f16 accumulates att across ALL h
// (512-deep chain, 8 independent accumulators). No per-h epilogue.
// ---------------------------------------------------------------------------
__global__ __launch_bounds__(256, 2) void k_gram2(const unsigned short* __restrict__ xh,
                                                  const unsigned* __restrict__ wsqH,
                                                  const unsigned* __restrict__ invnH,
                                                  unsigned short* __restrict__ attn) {
    int bid = blockIdx.x;
    int tb = bid & 511;
    int rg = bid >> 9;                  // 0..7
    int n0 = rg << 5;
    int tid = threadIdx.x;
    int wave = tid >> 6, lane = tid & 63;
    int m16 = lane & 15, quad = lane >> 4;
    int wcol = wave << 6;

    __shared__ unsigned wS[16 * 64];     // 4 KB: w^2 as packed f16 pairs [h][d/2]
    __shared__ unsigned ivS[16 * 256];   // 16 KB: invn dup-f16 [h][n]
    __shared__ float rsum[4][32];

    const unsigned short* Xb = xh + ((size_t)tb << 15);

    // ---- stage tables ----
    {
        uint4 v = *(const uint4*)(wsqH + (tid << 2));
        *(uint4*)(wS + (tid << 2)) = v;
    }
    {
        const unsigned* src = invnH + ((size_t)tb << 12);
        #pragma unroll
        for (int hh = 0; hh < 16; ++hh)
            ivS[(hh << 8) + tid] = src[(hh << 8) + tid];
    }

    // ---- resident raw fragments (packed f16) ----
    half8 Bf[4][4];                     // [ks][cb] = 64 VGPR
    #pragma unroll
    for (int ks = 0; ks < 4; ++ks)
        #pragma unroll
        for (int cb = 0; cb < 4; ++cb)
            Bf[ks][cb] = *(const half8*)(Xb + ((wcol + (cb << 4) + m16) << 7) + (ks << 5) + (quad << 3));

    half8 Af[2][4];                     // [rb][ks] = 32 VGPR
    #pragma unroll
    for (int rb = 0; rb < 2; ++rb)
        #pragma unroll
        for (int ks = 0; ks < 4; ++ks)
            Af[rb][ks] = *(const half8*)(Xb + ((n0 + (rb << 4) + m16) << 7) + (ks << 5) + (quad << 3));

    f32x4 att[2][4];
    #pragma unroll
    for (int rb = 0; rb < 2; ++rb)
        #pragma unroll
        for (int cb = 0; cb < 4; ++cb) att[rb][cb] = (f32x4){0.f, 0.f, 0.f, 0.f};

    __syncthreads();   // tables staged

    union H8 { half8 v; h2 p[4]; };

    #pragma unroll 1
    for (int h = 0; h < 16; ++h) {
        const unsigned* ivh = ivS + (h << 8);
        h2 ivr[2], ivc[4];
        #pragma unroll
        for (int rb = 0; rb < 2; ++rb) ivr[rb] = u2h(ivh[n0 + (rb << 4) + m16]);
        #pragma unroll
        for (int cb = 0; cb < 4; ++cb) ivc[cb] = u2h(ivh[wcol + (cb << 4) + m16]);

        #pragma unroll
        for (int ks = 0; ks < 4; ++ks) {
            uint4 wu = *(const uint4*)(wS + (h << 6) + (ks << 4) + (quad << 2));
            h2 w0 = u2h(wu.x), w1 = u2h(wu.y), w2 = u2h(wu.z), w3 = u2h(wu.w);

            H8 afr[2];
            #pragma unroll
            for (int rb = 0; rb < 2; ++rb) {
                H8 a; a.v = Af[rb][ks];
                afr[rb].p[0] = a.p[0] * (w0 * ivr[rb]);
                afr[rb].p[1] = a.p[1] * (w1 * ivr[rb]);
                afr[rb].p[2] = a.p[2] * (w2 * ivr[rb]);
                afr[rb].p[3] = a.p[3] * (w3 * ivr[rb]);
            }
            H8 bfr[4];
            #pragma unroll
            for (int cb = 0; cb < 4; ++cb) {
                H8 b; b.v = Bf[ks][cb];
                afr[0].p[0] = afr[0].p[0];   // no-op keep order
                bfr[cb].p[0] = b.p[0] * ivc[cb];
                bfr[cb].p[1] = b.p[1] * ivc[cb];
                bfr[cb].p[2] = b.p[2] * ivc[cb];
                bfr[cb].p[3] = b.p[3] * ivc[cb];
            }
            #pragma unroll
            for (int rb = 0; rb < 2; ++rb)
                #pragma unroll
                for (int cb = 0; cb < 4; ++cb)
                    att[rb][cb] = __builtin_amdgcn_mfma_f32_16x16x32_f16(afr[rb].v, bfr[cb].v, att[rb][cb], 0, 0, 0);
        }
    }

    // relu + rowsum + normalize (x0.7) -> bf16 attn  (relu(S)/16 trick: +16eps)
    float rs[2][4];
    #pragma unroll
    for (int rb = 0; rb < 2; ++rb)
        #pragma unroll
        for (int r = 0; r < 4; ++r) {
            float s = 0.f;
            #pragma unroll
            for (int cb = 0; cb < 4; ++cb) {
                float v = fmaxf(att[rb][cb][r], 0.0f);
                att[rb][cb][r] = v;
                s += v;
            }
            rs[rb][r] = s;
        }
    #pragma unroll
    for (int m = 1; m < 16; m <<= 1)
        #pragma unroll
        for (int rb = 0; rb < 2; ++rb)
            #pragma unroll
            for (int r = 0; r < 4; ++r)
                rs[rb][r] += __shfl_xor(rs[rb][r], m, 64);
    if (m16 == 0) {
        #pragma unroll
        for (int rb = 0; rb < 2; ++rb)
            #pragma unroll
            for (int r = 0; r < 4; ++r)
                rsum[wave][(rb << 4) + (quad << 2) + r] = rs[rb][r];
    }
    __syncthreads();

    unsigned short* outb = attn + ((size_t)tb << 16);
    #pragma unroll
    for (int rb = 0; rb < 2; ++rb) {
        #pragma unroll
        for (int r = 0; r < 4; ++r) {
            int row = (rb << 4) + (quad << 2) + r;
            float tot = rsum[0][row] + rsum[1][row] + rsum[2][row] + rsum[3][row];
            float inv = (1.0f - SKIPF) / (tot + 16.0f * EPSF);
            #pragma unroll
            for (int cb = 0; cb < 4; ++cb) {
                int col = (wave << 6) + (cb << 4) + m16;
                outb[((size_t)(n0 + row) << 8) + col] = f2bf(att[rb][cb][r] * inv);
            }
        }
    }
}

// ---------------------------------------------------------------------------
// scanlast: a=supports; a=0.3a+attn_t; write only A_15 (bf16). grid 2048x256.
// ---------------------------------------------------------------------------
__global__ __launch_bounds__(256) void k_scanlast(const float* __restrict__ supports,
                                                  const unsigned short* __restrict__ AttA,
                                                  unsigned short* __restrict__ Afin) {
    size_t flat = ((size_t)blockIdx.x * 256 + threadIdx.x) * 4;
    float4 s4 = *(const float4*)(supports + flat);
    float a0 = s4.x, a1 = s4.y, a2 = s4.z, a3 = s4.w;
    #pragma unroll
    for (int t = 0; t < TT; ++t) {
        const unsigned short* p = AttA + ((size_t)t << 21) + flat;
        uint2 u = *(const uint2*)p;
        a0 = SKIPF * a0 + bf2f((unsigned short)(u.x & 0xffff));
        a1 = SKIPF * a1 + bf2f((unsigned short)(u.x >> 16));
        a2 = SKIPF * a2 + bf2f((unsigned short)(u.y & 0xffff));
        a3 = SKIPF * a3 + bf2f((unsigned short)(u.y >> 16));
    }
    uint2 o;
    o.x = pack2(f2bf(a0), f2bf(a1));
    o.y = pack2(f2bf(a2), f2bf(a3));
    *(uint2*)(Afin + flat) = o;
}

// NOTE: AttA is indexed [tb][n][m] with tb = t*32+b; scanlast's flat index
// covers b,n,m for fixed t via offset t<<21 — consistent with gram2's tb.

// ---------------------------------------------------------------------------
// hTinit: hT0[b][d][n] = bf16(x15[b][n][d]) for b=0..31. grid 32*32 blocks.
// ---------------------------------------------------------------------------
__global__ __launch_bounds__(256) void k_hTinit(const float* __restrict__ x15,
                                                unsigned short* __restrict__ hT) {
    int bid = blockIdx.x;
    int b = bid >> 5; int r = bid & 31; int d0 = (r >> 3) << 5; int n0 = (r & 7) << 5;
    __shared__ float tl[32][33];
    int tid = threadIdx.x;
    int i = tid >> 5, j = tid & 31;
    #pragma unroll
    for (int s = 0; s < 4; ++s) {
        int nl = (s << 3) + i;
        tl[nl][j] = x15[((size_t)(b * 256 + n0 + nl) << 7) + d0 + j];
    }
    __syncthreads();
    #pragma unroll
    for (int s = 0; s < 4; ++s) {
        int dd = (s << 3) + i;
        hT[((size_t)(b * 128 + d0 + dd) << 8) + n0 + j] = f2bf(tl[j][dd]);
    }
}

// ---------------------------------------------------------------------------
// wprep: bf16-transposed weights WT[dout][k] + packed-f16 w^2 table for gram2
// ---------------------------------------------------------------------------
__global__ __launch_bounds__(256) void k_wprep(const float* __restrict__ Wa,
                                               const float* __restrict__ Wr,
                                               const float* __restrict__ Wz,
                                               const float* __restrict__ Wh,
                                               const float* __restrict__ Wgl,
                                               unsigned short* __restrict__ WaT,
                                               unsigned short* __restrict__ WrT,
                                               unsigned short* __restrict__ WzT,
                                               unsigned short* __restrict__ WhT,
                                               unsigned* __restrict__ wsqH) {
    int idx = blockIdx.x * 256 + threadIdx.x;     // 0..32767
    if (idx < 16384) {
        int dout = idx >> 7, din = idx & 127;
        WaT[idx] = f2bf(Wa[(din << 7) + dout]);
    }
    if (idx < 1024) {
        // wsqH[h][j] = packed f16 (w[2j]^2, w[2j+1]^2), h = idx>>6, j = idx&63
        int h = idx >> 6, j = idx & 63;
        float w0 = Wgl[(h << 7) + (j << 1)];
        float w1 = Wgl[(h << 7) + (j << 1) + 1];
        wsqH[idx] = pkrtz(w0 * w0, w1 * w1);
    }
    {
        int dout = idx >> 8, dk = idx & 255;
        WrT[idx] = f2bf(Wr[(dk << 7) + dout]);
        WzT[idx] = f2bf(Wz[(dk << 7) + dout]);
        WhT[idx] = f2bf(Wh[(dk << 7) + dout]);
    }
}

// ---------------------------------------------------------------------------
// step: fused GGNN/GRU step for t=15 only: b = 0..31, 32-row tiles.
// h state in hT (bf16, [b][d][n]). grid = 8 rg x 32 b = 256 blocks.
// ---------------------------------------------------------------------------
__global__ __launch_bounds__(256) void k_step(
    const unsigned short* __restrict__ Afin,
    const unsigned short* __restrict__ hT,
    const unsigned short* __restrict__ WaT, const float* __restrict__ ba,
    const unsigned short* __restrict__ WrT, const float* __restrict__ br,
    const unsigned short* __restrict__ WzT, const float* __restrict__ bz,
    const unsigned short* __restrict__ WhT, const float* __restrict__ bh,
    unsigned short* __restrict__ hT_o) {

    int bid = blockIdx.x;
    int b = bid & 31, rg = bid >> 5;
    int n0 = rg << 5;
    int tid = threadIdx.x;
    int wave = tid >> 6, lane = tid & 63;
    int m16 = lane & 15, quad = lane >> 4;
    int wcol = wave << 5;

    __shared__ unsigned short msgS[32 * 136];
    __shared__ unsigned short ahS[32 * 264];   // k 0..127 = a, 128..255 = h (later r*h)

    const unsigned short* hTb = hT + ((size_t)b << 15);

    // stage h-half of ahS from hT (transpose: ahS[row][128+d] = hT[d][n0+row])
    #pragma unroll
    for (int j = 0; j < 16; ++j) {
        int idx = (j << 8) + tid;            // 0..4095
        int d = idx >> 5, row = idx & 31;
        ahS[row * 264 + 128 + d] = hTb[((size_t)d << 8) + n0 + row];
    }

    // ---- bmm: msg = A_tile @ h  (K=256) ----
    f32x4 acc[2][2];
    #pragma unroll
    for (int rb = 0; rb < 2; ++rb)
        #pragma unroll
        for (int cb = 0; cb < 2; ++cb) acc[rb][cb] = (f32x4){0.f, 0.f, 0.f, 0.f};

    const unsigned short* Ab = Afin + ((size_t)b << 16) + ((size_t)n0 << 8);
    #pragma unroll 2
    for (int ks = 0; ks < 8; ++ks) {
        bf16x8 af[2], bf[2];
        #pragma unroll
        for (int rb = 0; rb < 2; ++rb)
            af[rb] = *(const bf16x8*)(Ab + (((rb << 4) + m16) << 8) + (ks << 5) + (quad << 3));
        #pragma unroll
        for (int cb = 0; cb < 2; ++cb)
            bf[cb] = *(const bf16x8*)(hTb + ((wcol + (cb << 4) + m16) << 8) + (ks << 5) + (quad << 3));
        #pragma unroll
        for (int rb = 0; rb < 2; ++rb)
            #pragma unroll
            for (int cb = 0; cb < 2; ++cb)
                acc[rb][cb] = __builtin_amdgcn_mfma_f32_16x16x32_bf16(af[rb], bf[cb], acc[rb][cb], 0, 0, 0);
    }
    #pragma unroll
    for (int rb = 0; rb < 2; ++rb)
        #pragma unroll
        for (int cb = 0; cb < 2; ++cb)
            #pragma unroll
            for (int r = 0; r < 4; ++r)
                msgS[((rb << 4) + (quad << 2) + r) * 136 + wcol + (cb << 4) + m16] = f2bf(acc[rb][cb][r]);
    __syncthreads();   // covers h-half staging too

    // ---- a = msg @ Wa + ba ----
    #pragma unroll
    for (int rb = 0; rb < 2; ++rb)
        #pragma unroll
        for (int cb = 0; cb < 2; ++cb) acc[rb][cb] = (f32x4){0.f, 0.f, 0.f, 0.f};
    #pragma unroll
    for (int ks = 0; ks < 4; ++ks) {
        bf16x8 af[2], bf[2];
        #pragma unroll
        for (int rb = 0; rb < 2; ++rb)
            af[rb] = *(const bf16x8*)(msgS + ((rb << 4) + m16) * 136 + (ks << 5) + (quad << 3));
        #pragma unroll
        for (int cb = 0; cb < 2; ++cb)
            bf[cb] = *(const bf16x8*)(WaT + ((wcol + (cb << 4) + m16) << 7) + (ks << 5) + (quad << 3));
        #pragma unroll
        for (int rb = 0; rb < 2; ++rb)
            #pragma unroll
            for (int cb = 0; cb < 2; ++cb)
                acc[rb][cb] = __builtin_amdgcn_mfma_f32_16x16x32_bf16(af[rb], bf[cb], acc[rb][cb], 0, 0, 0);
    }
    {
        float bav[2];
        #pragma unroll
        for (int cb = 0; cb < 2; ++cb) bav[cb] = ba[wcol + (cb << 4) + m16];
        #pragma unroll
        for (int rb = 0; rb < 2; ++rb)
            #pragma unroll
            for (int cb = 0; cb < 2; ++cb)
                #pragma unroll
                for (int r = 0; r < 4; ++r)
                    ahS[((rb << 4) + (quad << 2) + r) * 264 + wcol + (cb << 4) + m16] =
                        f2bf(acc[rb][cb][r] + bav[cb]);
    }
    __syncthreads();

    // h_old (for r*h and final update): uint2 = 4 consecutive n at fixed col
    float hv[2][2][4];
    #pragma unroll
    for (int rb = 0; rb < 2; ++rb)
        #pragma unroll
        for (int cb = 0; cb < 2; ++cb) {
            int col = wcol + (cb << 4) + m16;
            uint2 u = *(const uint2*)(hTb + ((size_t)col << 8) + n0 + (rb << 4) + (quad << 2));
            hv[rb][cb][0] = bf2f((unsigned short)(u.x & 0xffff));
            hv[rb][cb][1] = bf2f((unsigned short)(u.x >> 16));
            hv[rb][cb][2] = bf2f((unsigned short)(u.y & 0xffff));
            hv[rb][cb][3] = bf2f((unsigned short)(u.y >> 16));
        }

    // ---- r and z ----
    f32x4 racc[2][2], zacc[2][2];
    #pragma unroll
    for (int rb = 0; rb < 2; ++rb)
        #pragma unroll
        for (int cb = 0; cb < 2; ++cb) {
            racc[rb][cb] = (f32x4){0.f, 0.f, 0.f, 0.f};
            zacc[rb][cb] = (f32x4){0.f, 0.f, 0.f, 0.f};
        }
    #pragma unroll 2
    for (int ks = 0; ks < 8; ++ks) {
        bf16x8 af[2], bfr[2], bfz[2];
        #pragma unroll
        for (int rb = 0; rb < 2; ++rb)
            af[rb] = *(const bf16x8*)(ahS + ((rb << 4) + m16) * 264 + (ks << 5) + (quad << 3));
        #pragma unroll
        for (int cb = 0; cb < 2; ++cb) {
            int dout = wcol + (cb << 4) + m16;
            bfr[cb] = *(const bf16x8*)(WrT + (dout << 8) + (ks << 5) + (quad << 3));
            bfz[cb] = *(const bf16x8*)(WzT + (dout << 8) + (ks << 5) + (quad << 3));
        }
        #pragma unroll
        for (int rb = 0; rb < 2; ++rb)
            #pragma unroll
            for (int cb = 0; cb < 2; ++cb) {
                racc[rb][cb] = __builtin_amdgcn_mfma_f32_16x16x32_bf16(af[rb], bfr[cb], racc[rb][cb], 0, 0, 0);
                zacc[rb][cb] = __builtin_amdgcn_mfma_f32_16x16x32_bf16(af[rb], bfz[cb], zacc[rb][cb], 0, 0, 0);
            }
    }
    float zv[2][2][4];
    {
        float brv[2], bzv[2];
        #pragma unroll
        for (int cb = 0; cb < 2; ++cb) {
            brv[cb] = br[wcol + (cb << 4) + m16];
            bzv[cb] = bz[wcol + (cb << 4) + m16];
        }
        #pragma unroll
        for (int rb = 0; rb < 2; ++rb)
            #pragma unroll
            for (int cb = 0; cb < 2; ++cb)
                #pragma unroll
                for (int r = 0; r < 4; ++r) {
                    racc[rb][cb][r] = sigmoidf_(racc[rb][cb][r] + brv[cb]);
                    zv[rb][cb][r]  = sigmoidf_(zacc[rb][cb][r] + bzv[cb]);
                }
    }
    __syncthreads();   // all ahS reads done -> safe to overwrite h-half

    #pragma unroll
    for (int rb = 0; rb < 2; ++rb)
        #pragma unroll
        for (int cb = 0; cb < 2; ++cb)
            #pragma unroll
            for (int r = 0; r < 4; ++r)
                ahS[((rb << 4) + (quad << 2) + r) * 264 + 128 + wcol + (cb << 4) + m16] =
                    f2bf(racc[rb][cb][r] * hv[rb][cb][r]);
    __syncthreads();

    // ---- h_tilde ----
    #pragma unroll
    for (int rb = 0; rb < 2; ++rb)
        #pragma unroll
        for (int cb = 0; cb < 2; ++cb) acc[rb][cb] = (f32x4){0.f, 0.f, 0.f, 0.f};
    #pragma unroll 2
    for (int ks = 0; ks < 8; ++ks) {
        bf16x8 af[2], bf[2];
        #pragma unroll
        for (int rb = 0; rb < 2; ++rb)
            af[rb] = *(const bf16x8*)(ahS + ((rb << 4) + m16) * 264 + (ks << 5) + (quad << 3));
        #pragma unroll
        for (int cb = 0; cb < 2; ++cb)
            bf[cb] = *(const bf16x8*)(WhT + ((wcol + (cb << 4) + m16) << 8) + (ks << 5) + (quad << 3));
        #pragma unroll
        for (int rb = 0; rb < 2; ++rb)
            #pragma unroll
            for (int cb = 0; cb < 2; ++cb)
                acc[rb][cb] = __builtin_amdgcn_mfma_f32_16x16x32_bf16(af[rb], bf[cb], acc[rb][cb], 0, 0, 0);
    }

    // ---- update + writes (hT only) ----
    {
        float bhv[2];
        #pragma unroll
        for (int cb = 0; cb < 2; ++cb) bhv[cb] = bh[wcol + (cb << 4) + m16];
        #pragma unroll
        for (int rb = 0; rb < 2; ++rb)
            #pragma unroll
            for (int cb = 0; cb < 2; ++cb) {
                int col = wcol + (cb << 4) + m16;
                unsigned short pk[4];
                #pragma unroll
                for (int r = 0; r < 4; ++r) {
                    float ht = tanhf_(acc[rb][cb][r] + bhv[cb]);
                    float hn = hv[rb][cb][r] + zv[rb][cb][r] * (ht - hv[rb][cb][r]);
                    pk[r] = f2bf(hn);
                }
                uint2 p;
                p.x = pack2(pk[0], pk[1]); p.y = pack2(pk[2], pk[3]);
                *(uint2*)(hT_o + ((size_t)(b * 128 + col) << 8) + n0 + (rb << 4) + (quad << 2)) = p;
            }
    }
}

// ---------------------------------------------------------------------------
// fc: logits[b,c] = sum over col-major h (hT1, b slice) + bfc. grid = 512.
// ---------------------------------------------------------------------------
__global__ __launch_bounds__(256) void k_fc(const unsigned short* __restrict__ hT,
                                            const float* __restrict__ Wfc,
                                            const float* __restrict__ bfc,
                                            float* __restrict__ out) {
    int bid = blockIdx.x;
    int b = bid >> 4, part = bid & 15;
    int tid = threadIdx.x;
    const unsigned short* hp = hT + ((size_t)b << 15);
    int i = part * 2048 + tid * 8;       // linear col-major: i = d*256 + n
    int d = i >> 8, n = i & 255;
    uint4 hu = *(const uint4*)(hp + i);
    unsigned short hs[8];
    hs[0] = hu.x & 0xffff; hs[1] = hu.x >> 16;
    hs[2] = hu.y & 0xffff; hs[3] = hu.y >> 16;
    hs[4] = hu.z & 0xffff; hs[5] = hu.z >> 16;
    hs[6] = hu.w & 0xffff; hs[7] = hu.w >> 16;
    float a0 = 0.f, a1 = 0.f;
    #pragma unroll
    for (int k = 0; k < 8; ++k) {
        float v = bf2f(hs[k]);
        const float2 w = *(const float2*)(Wfc + ((size_t)(n + k) * 128 + d) * 2);
        a0 = fmaf(v, w.x, a0);
        a1 = fmaf(v, w.y, a1);
    }
    int wave = tid >> 6, lane = tid & 63;
    #pragma unroll
    for (int off = 32; off; off >>= 1) {
        a0 += __shfl_down(a0, off, 64);
        a1 += __shfl_down(a1, off, 64);
    }
    __shared__ float r0[4], r1[4];
    if (lane == 0) { r0[wave] = a0; r1[wave] = a1; }
    __syncthreads();
    if (tid == 0) {
        float s0 = r0[0] + r0[1] + r0[2] + r0[3];
        float s1 = r1[0] + r1[1] + r1[2] + r1[3];
        if (part == 0) { s0 += bfc[0]; s1 += bfc[1]; }
        atomicAdd(&out[b * 2 + 0], s0);
        atomicAdd(&out[b * 2 + 1], s1);
    }
}

// ---------------------------------------------------------------------------
extern "C" void kernel_launch(void* const* d_in, const int* in_sizes, int n_in,
                              void* d_out, int out_size, void* d_ws, size_t ws_size,
                              hipStream_t stream) {
    const float* x_all    = (const float*)d_in[0];
    const float* supports = (const float*)d_in[1];
    const float* Wgl = (const float*)d_in[2];
    const float* Wa  = (const float*)d_in[3];
    const float* ba  = (const float*)d_in[4];
    const float* Wr  = (const float*)d_in[5];
    const float* br  = (const float*)d_in[6];
    const float* Wz  = (const float*)d_in[7];
    const float* bz  = (const float*)d_in[8];
    const float* Wh  = (const float*)d_in[9];
    const float* bh  = (const float*)d_in[10];
    const float* Wfc = (const float*)d_in[11];
    const float* bfc = (const float*)d_in[12];
    float* out = (float*)d_out;

    char* p = (char*)d_ws;
    auto alloc = [&](size_t bytes) { char* r = p; p += (bytes + 255) & ~(size_t)255; return r; };

    unsigned short* AttA = (unsigned short*)alloc((size_t)TT * BB * NN * NN * 2);  // 64 MB
    unsigned short* xh   = (unsigned short*)alloc((size_t)TT * BB * NN * DD * 2);  // 32 MB (f16)
    unsigned* invnH      = (unsigned*)alloc((size_t)TT * BB * 16 * NN * 4);        // 8 MB (dup f16)
    unsigned short* Afin = (unsigned short*)alloc((size_t)BB * NN * NN * 2);       // 4 MB
    unsigned short* hT0  = (unsigned short*)alloc((size_t)BB * DD * NN * 2);       // 2 MB
    unsigned short* hT1  = (unsigned short*)alloc((size_t)BB * DD * NN * 2);       // 2 MB
    unsigned short* WaT  = (unsigned short*)alloc(128 * 128 * 2);
    unsigned short* WrT  = (unsigned short*)alloc(256 * 128 * 2);
    unsigned short* WzT  = (unsigned short*)alloc(256 * 128 * 2);
    unsigned short* WhT  = (unsigned short*)alloc(256 * 128 * 2);
    unsigned* wsqH       = (unsigned*)alloc(16 * 64 * 4);                          // 4 KB
    // total ~112.5 MB

    k_wprep<<<128, 256, 0, stream>>>(Wa, Wr, Wz, Wh, Wgl, WaT, WrT, WzT, WhT, wsqH);
    k_norms<<<TT * BB * 16, 256, 0, stream>>>(x_all, Wgl, xh, invnH);

    // attention path: all 16 t in one dispatch
    k_gram2<<<8 * TT * BB, 256, 0, stream>>>(xh, wsqH, invnH, AttA);
    k_scanlast<<<2048, 256, 0, stream>>>(supports, AttA, Afin);

    // GRU path: ONLY t=15 is live (reference uses outs[-1] only)
    const float* x15 = x_all + (size_t)15 * BB * NN * DD;
    k_hTinit<<<BB * 32, 256, 0, stream>>>(x15, hT0);

    const unsigned short* hT_in = hT0;
    for (int s = 0; s < NSTEPS; ++s) {
        unsigned short* hTo = (s & 1) ? hT0 : hT1;
        k_step<<<8 * BB, 256, 0, stream>>>(Afin, hT_in,
                                           WaT, ba, WrT, br, WzT, bz, WhT, bh,
                                           hTo);
        hT_in = hTo;
    }
    // after 5 steps (s=4) final h is in hT1
    hipMemsetAsync(d_out, 0, (size_t)out_size * sizeof(float), stream);
    k_fc<<<BB * 16, 256, 0, stream>>>(hT1, Wfc, bfc, out);
}

// Round 6
// 372.009 us; speedup vs baseline: 1.3072x; 1.0361x over previous
//
#include <hip/hip_runtime.h>
#include <math.h>

#define TT 16
#define BB 32
#define NN 256
#define DD 128
#define NSTEPS 5
#define SKIPF 0.3f
#define EPSF 1e-8f

// R7: only outs[-1] is live -> GRU for t<15 is dead code.
// R9: V eliminated; gram computed from staged low-precision x.
// R10: register-resident gram2. R11: LDS tables (issue-saturated at 91%).
// R12: f16 packed-math gram (VALU 62 + MFMA 41 = 103% -> pure inst-count).
// R13/R14: +64x64 gram tiles +MFMA-norms k_prep -> two container failures
//   (infra-suspect: 406s npz push on R13; no-timing acquisition fail R14).
// R15 (this round): BISECTION. Verified R12 k_norms (passed @385us) +
//   R13's 64x64-tile gram2 only. k_prep withheld until a clean run.

typedef __attribute__((ext_vector_type(8))) short bf16x8;
typedef __attribute__((ext_vector_type(4))) float f32x4;
typedef __attribute__((ext_vector_type(8))) _Float16 half8;
typedef __attribute__((ext_vector_type(2))) _Float16 h2;

__device__ __forceinline__ unsigned short f2bf(float f) {
    union { float f; unsigned u; } v; v.f = f;
    unsigned r = (v.u + 0x7FFF + ((v.u >> 16) & 1)) >> 16;
    return (unsigned short)r;
}
__device__ __forceinline__ float bf2f(unsigned short u) {
    union { unsigned u; float f; } v; v.u = ((unsigned)u) << 16; return v.f;
}
__device__ __forceinline__ unsigned pack2(unsigned short a, unsigned short b) {
    return (unsigned)a | ((unsigned)b << 16);
}
// packed f32->f16 convert (RTZ), 1 inst for 2 elems
__device__ __forceinline__ unsigned pkrtz(float a, float b) {
    unsigned r;
    asm("v_cvt_pkrtz_f16_f32 %0, %1, %2" : "=v"(r) : "v"(a), "v"(b));
    return r;
}
__device__ __forceinline__ h2 u2h(unsigned u) {
    union { unsigned u; h2 h; } v; v.u = u; return v.h;
}
__device__ __forceinline__ float sigmoidf_(float x) {
    return 1.0f / (1.0f + __expf(-x));
}
__device__ __forceinline__ float tanhf_(float x) {
    return 1.0f - 2.0f / (__expf(2.0f * x) + 1.0f);
}

// ---------------------------------------------------------------------------
// norms (VERIFIED R12 version): per block (tb, 16-row group):
//   xh = f16(x) written out (32 MB total)
//   invnH[tb][h][n] = dup-f16( 1/(sqrt(sum_d x^2 w^2)+eps) )
// grid = TT*BB*16 blocks, 256 threads = 16 n x 16 h.
// ---------------------------------------------------------------------------
__global__ __launch_bounds__(256) void k_norms(const float* __restrict__ x,
                                               const float* __restrict__ Wgl,
                                               unsigned short* __restrict__ xh,
                                               unsigned* __restrict__ invnH) {
    int bid = blockIdx.x;
    int tb = bid >> 4, ng = bid & 15;
    int n0 = ng << 4;
    int tid = threadIdx.x;
    __shared__ float xs[16][132];    // pad 132: 2-way aliasing = free
    __shared__ float ws[16][128];    // w^2, h-row broadcast reads

    {
        int r = tid >> 4, c = (tid & 15) << 3;
        const float* src = x + ((size_t)(tb * 256 + n0 + r) << 7) + c;
        float4 a = *(const float4*)src;
        float4 b = *(const float4*)(src + 4);
        *(float4*)&xs[r][c] = a;
        *(float4*)&xs[r][c + 4] = b;
        // f16 conversion of the same 8 values -> xh
        uint4 o;
        o.x = pkrtz(a.x, a.y); o.y = pkrtz(a.z, a.w);
        o.z = pkrtz(b.x, b.y); o.w = pkrtz(b.z, b.w);
        *(uint4*)(xh + ((size_t)(tb * 256 + n0 + r) << 7) + c) = o;
        const float* wsrc = Wgl + (r << 7) + c;   // r doubles as h
        float4 wa = *(const float4*)wsrc;
        float4 wb = *(const float4*)(wsrc + 4);
        ws[r][c + 0] = wa.x * wa.x; ws[r][c + 1] = wa.y * wa.y;
        ws[r][c + 2] = wa.z * wa.z; ws[r][c + 3] = wa.w * wa.w;
        ws[r][c + 4] = wb.x * wb.x; ws[r][c + 5] = wb.y * wb.y;
        ws[r][c + 6] = wb.z * wb.z; ws[r][c + 7] = wb.w * wb.w;
    }
    __syncthreads();

    int n_l = tid & 15, h = tid >> 4;
    float s = 0.f;
    #pragma unroll
    for (int d = 0; d < 128; d += 4) {
        float4 xv = *(const float4*)&xs[n_l][d];
        float4 wv = *(const float4*)&ws[h][d];
        s = fmaf(xv.x * xv.x, wv.x, s);
        s = fmaf(xv.y * xv.y, wv.y, s);
        s = fmaf(xv.z * xv.z, wv.z, s);
        s = fmaf(xv.w * xv.w, wv.w, s);
    }
    float inv = 1.0f / (sqrtf(s) + EPSF);
    invnH[((size_t)(tb * 16 + h) << 8) + n0 + n_l] = pkrtz(inv, inv);
}

// ---------------------------------------------------------------------------
// gram2 (f16 packed, 64x64 wave tiles):
//   attn_t = 0.7*rownorm(relu(sum_h D_h X W2_h X^T D_h)).
// grid = 4 rg x 512 tb = 2048 blocks, 256 threads, LDS 21 KB.
// Block = 64 rows x 256 cols; wave = 64 rows x 64 cols. Af (64 VGPR),
// Bf (64 VGPR), acc (64 VGPR) resident. Per h: A-frag = A*(w^2*invr),
// B-frag = B*invc via v_pk_mul_f16; MFMA f16 accumulates att across all h.
// ---------------------------------------------------------------------------
__global__ __launch_bounds__(256, 2) void k_gram2(const unsigned short* __restrict__ xhp,
                                                  const unsigned* __restrict__ wsqH,
                                                  const unsigned* __restrict__ invnH,
                                                  unsigned short* __restrict__ attn) {
    int bid = blockIdx.x;
    int tb = bid & 511;
    int rg = bid >> 9;                  // 0..3
    int n0 = rg << 6;
    int tid = threadIdx.x;
    int wave = tid >> 6, lane = tid & 63;
    int m16 = lane & 15, quad = lane >> 4;
    int wcol = wave << 6;

    __shared__ unsigned wS[16 * 64];     // 4 KB: w^2 packed f16 pairs [h][d/2]
    __shared__ unsigned ivS[16 * 256];   // 16 KB: invn dup-f16 [h][n]
    __shared__ float rsum[4][64];        // 1 KB

    const unsigned short* Xb = xhp + ((size_t)tb << 15);

    // ---- stage tables ----
    {
        uint4 v = *(const uint4*)(wsqH + (tid << 2));
        *(uint4*)(wS + (tid << 2)) = v;
    }
    {
        const unsigned* src = invnH + ((size_t)tb << 12);
        #pragma unroll
        for (int hh = 0; hh < 16; ++hh)
            ivS[(hh << 8) + tid] = src[(hh << 8) + tid];
    }

    // ---- resident raw fragments (packed f16) ----
    half8 Bf[4][4];                     // [ks][cb] = 64 VGPR (wave's 64 cols)
    #pragma unroll
    for (int ks = 0; ks < 4; ++ks)
        #pragma unroll
        for (int cb = 0; cb < 4; ++cb)
            Bf[ks][cb] = *(const half8*)(Xb + ((wcol + (cb << 4) + m16) << 7) + (ks << 5) + (quad << 3));

    half8 Af[4][4];                     // [rb][ks] = 64 VGPR (block's 64 rows)
    #pragma unroll
    for (int rb = 0; rb < 4; ++rb)
        #pragma unroll
        for (int ks = 0; ks < 4; ++ks)
            Af[rb][ks] = *(const half8*)(Xb + ((n0 + (rb << 4) + m16) << 7) + (ks << 5) + (quad << 3));

    f32x4 att[4][4];
    #pragma unroll
    for (int rb = 0; rb < 4; ++rb)
        #pragma unroll
        for (int cb = 0; cb < 4; ++cb) att[rb][cb] = (f32x4){0.f, 0.f, 0.f, 0.f};

    __syncthreads();   // tables staged

    union H8 { half8 v; h2 p[4]; };

    #pragma unroll 1
    for (int h = 0; h < 16; ++h) {
        const unsigned* ivh = ivS + (h << 8);
        h2 ivr[4], ivc[4];
        #pragma unroll
        for (int rb = 0; rb < 4; ++rb) ivr[rb] = u2h(ivh[n0 + (rb << 4) + m16]);
        #pragma unroll
        for (int cb = 0; cb < 4; ++cb) ivc[cb] = u2h(ivh[wcol + (cb << 4) + m16]);

        #pragma unroll
        for (int ks = 0; ks < 4; ++ks) {
            uint4 wu = *(const uint4*)(wS + (h << 6) + (ks << 4) + (quad << 2));
            h2 w0 = u2h(wu.x), w1 = u2h(wu.y), w2 = u2h(wu.z), w3 = u2h(wu.w);

            H8 afr[4];
            #pragma unroll
            for (int rb = 0; rb < 4; ++rb) {
                H8 a; a.v = Af[rb][ks];
                h2 s = ivr[rb];
                afr[rb].p[0] = a.p[0] * (w0 * s);
                afr[rb].p[1] = a.p[1] * (w1 * s);
                afr[rb].p[2] = a.p[2] * (w2 * s);
                afr[rb].p[3] = a.p[3] * (w3 * s);
            }
            #pragma unroll
            for (int cb = 0; cb < 4; ++cb) {
                H8 b; b.v = Bf[ks][cb];
                H8 bf;
                bf.p[0] = b.p[0] * ivc[cb];
                bf.p[1] = b.p[1] * ivc[cb];
                bf.p[2] = b.p[2] * ivc[cb];
                bf.p[3] = b.p[3] * ivc[cb];
                #pragma unroll
                for (int rb = 0; rb < 4; ++rb)
                    att[rb][cb] = __builtin_amdgcn_mfma_f32_16x16x32_f16(afr[rb].v, bf.v, att[rb][cb], 0, 0, 0);
            }
        }
    }

    // relu + rowsum + normalize (x0.7) -> bf16 attn  (relu(S)/16 trick: +16eps)
    float rs[4][4];
    #pragma unroll
    for (int rb = 0; rb < 4; ++rb)
        #pragma unroll
        for (int r = 0; r < 4; ++r) {
            float s = 0.f;
            #pragma unroll
            for (int cb = 0; cb < 4; ++cb) {
                float v = fmaxf(att[rb][cb][r], 0.0f);
                att[rb][cb][r] = v;
                s += v;
            }
            rs[rb][r] = s;
        }
    #pragma unroll
    for (int m = 1; m < 16; m <<= 1)
        #pragma unroll
        for (int rb = 0; rb < 4; ++rb)
            #pragma unroll
            for (int r = 0; r < 4; ++r)
                rs[rb][r] += __shfl_xor(rs[rb][r], m, 64);
    if (m16 == 0) {
        #pragma unroll
        for (int rb = 0; rb < 4; ++rb)
            #pragma unroll
            for (int r = 0; r < 4; ++r)
                rsum[wave][(rb << 4) + (quad << 2) + r] = rs[rb][r];
    }
    __syncthreads();

    unsigned short* outb = attn + ((size_t)tb << 16);
    #pragma unroll
    for (int rb = 0; rb < 4; ++rb) {
        #pragma unroll
        for (int r = 0; r < 4; ++r) {
            int row = (rb << 4) + (quad << 2) + r;
            float tot = rsum[0][row] + rsum[1][row] + rsum[2][row] + rsum[3][row];
            float inv = (1.0f - SKIPF) / (tot + 16.0f * EPSF);
            #pragma unroll
            for (int cb = 0; cb < 4; ++cb) {
                int col = wcol + (cb << 4) + m16;
                outb[((size_t)(n0 + row) << 8) + col] = f2bf(att[rb][cb][r] * inv);
            }
        }
    }
}

// ---------------------------------------------------------------------------
// scanlast: a=supports; a=0.3a+attn_t; write only A_15 (bf16). grid 2048x256.
// ---------------------------------------------------------------------------
__global__ __launch_bounds__(256) void k_scanlast(const float* __restrict__ supports,
                                                  const unsigned short* __restrict__ AttA,
                                                  unsigned short* __restrict__ Afin) {
    size_t flat = ((size_t)blockIdx.x * 256 + threadIdx.x) * 4;
    float4 s4 = *(const float4*)(supports + flat);
    float a0 = s4.x, a1 = s4.y, a2 = s4.z, a3 = s4.w;
    #pragma unroll
    for (int t = 0; t < TT; ++t) {
        const unsigned short* p = AttA + ((size_t)t << 21) + flat;
        uint2 u = *(const uint2*)p;
        a0 = SKIPF * a0 + bf2f((unsigned short)(u.x & 0xffff));
        a1 = SKIPF * a1 + bf2f((unsigned short)(u.x >> 16));
        a2 = SKIPF * a2 + bf2f((unsigned short)(u.y & 0xffff));
        a3 = SKIPF * a3 + bf2f((unsigned short)(u.y >> 16));
    }
    uint2 o;
    o.x = pack2(f2bf(a0), f2bf(a1));
    o.y = pack2(f2bf(a2), f2bf(a3));
    *(uint2*)(Afin + flat) = o;
}

// NOTE: AttA is indexed [tb][n][m] with tb = t*32+b; scanlast's flat index
// covers b,n,m for fixed t via offset t<<21 — consistent with gram2's tb.

// ---------------------------------------------------------------------------
// hTinit: hT0[b][d][n] = bf16(x15[b][n][d]) for b=0..31. grid 32*32 blocks.
// ---------------------------------------------------------------------------
__global__ __launch_bounds__(256) void k_hTinit(const float* __restrict__ x15,
                                                unsigned short* __restrict__ hT) {
    int bid = blockIdx.x;
    int b = bid >> 5; int r = bid & 31; int d0 = (r >> 3) << 5; int n0 = (r & 7) << 5;
    __shared__ float tl[32][33];
    int tid = threadIdx.x;
    int i = tid >> 5, j = tid & 31;
    #pragma unroll
    for (int s = 0; s < 4; ++s) {
        int nl = (s << 3) + i;
        tl[nl][j] = x15[((size_t)(b * 256 + n0 + nl) << 7) + d0 + j];
    }
    __syncthreads();
    #pragma unroll
    for (int s = 0; s < 4; ++s) {
        int dd = (s << 3) + i;
        hT[((size_t)(b * 128 + d0 + dd) << 8) + n0 + j] = f2bf(tl[j][dd]);
    }
}

// ---------------------------------------------------------------------------
// wprep: bf16-transposed weights WT[dout][k] + packed-f16 w^2 table
// ---------------------------------------------------------------------------
__global__ __launch_bounds__(256) void k_wprep(const float* __restrict__ Wa,
                                               const float* __restrict__ Wr,
                                               const float* __restrict__ Wz,
                                               const float* __restrict__ Wh,
                                               const float* __restrict__ Wgl,
                                               unsigned short* __restrict__ WaT,
                                               unsigned short* __restrict__ WrT,
                                               unsigned short* __restrict__ WzT,
                                               unsigned short* __restrict__ WhT,
                                               unsigned* __restrict__ wsqH) {
    int idx = blockIdx.x * 256 + threadIdx.x;     // 0..32767
    if (idx < 16384) {
        int dout = idx >> 7, din = idx & 127;
        WaT[idx] = f2bf(Wa[(din << 7) + dout]);
    }
    if (idx < 1024) {
        // wsqH[h][j] = packed f16 (w[2j]^2, w[2j+1]^2)
        int h = idx >> 6, j = idx & 63;
        float w0 = Wgl[(h << 7) + (j << 1)];
        float w1 = Wgl[(h << 7) + (j << 1) + 1];
        wsqH[idx] = pkrtz(w0 * w0, w1 * w1);
    }
    {
        int dout = idx >> 8, dk = idx & 255;
        WrT[idx] = f2bf(Wr[(dk << 7) + dout]);
        WzT[idx] = f2bf(Wz[(dk << 7) + dout]);
        WhT[idx] = f2bf(Wh[(dk << 7) + dout]);
    }
}

// ---------------------------------------------------------------------------
// step: fused GGNN/GRU step for t=15 only: b = 0..31, 32-row tiles.
// h state in hT (bf16, [b][d][n]). grid = 8 rg x 32 b = 256 blocks.
// ---------------------------------------------------------------------------
__global__ __launch_bounds__(256) void k_step(
    const unsigned short* __restrict__ Afin,
    const unsigned short* __restrict__ hT,
    const unsigned short* __restrict__ WaT, const float* __restrict__ ba,
    const unsigned short* __restrict__ WrT, const float* __restrict__ br,
    const unsigned short* __restrict__ WzT, const float* __restrict__ bz,
    const unsigned short* __restrict__ WhT, const float* __restrict__ bh,
    unsigned short* __restrict__ hT_o) {

    int bid = blockIdx.x;
    int b = bid & 31, rg = bid >> 5;
    int n0 = rg << 5;
    int tid = threadIdx.x;
    int wave = tid >> 6, lane = tid & 63;
    int m16 = lane & 15, quad = lane >> 4;
    int wcol = wave << 5;

    __shared__ unsigned short msgS[32 * 136];
    __shared__ unsigned short ahS[32 * 264];   // k 0..127 = a, 128..255 = h (later r*h)

    const unsigned short* hTb = hT + ((size_t)b << 15);

    // stage h-half of ahS from hT (transpose: ahS[row][128+d] = hT[d][n0+row])
    #pragma unroll
    for (int j = 0; j < 16; ++j) {
        int idx = (j << 8) + tid;            // 0..4095
        int d = idx >> 5, row = idx & 31;
        ahS[row * 264 + 128 + d] = hTb[((size_t)d << 8) + n0 + row];
    }

    // ---- bmm: msg = A_tile @ h  (K=256) ----
    f32x4 acc[2][2];
    #pragma unroll
    for (int rb = 0; rb < 2; ++rb)
        #pragma unroll
        for (int cb = 0; cb < 2; ++cb) acc[rb][cb] = (f32x4){0.f, 0.f, 0.f, 0.f};

    const unsigned short* Ab = Afin + ((size_t)b << 16) + ((size_t)n0 << 8);
    #pragma unroll 2
    for (int ks = 0; ks < 8; ++ks) {
        bf16x8 af[2], bf[2];
        #pragma unroll
        for (int rb = 0; rb < 2; ++rb)
            af[rb] = *(const bf16x8*)(Ab + (((rb << 4) + m16) << 8) + (ks << 5) + (quad << 3));
        #pragma unroll
        for (int cb = 0; cb < 2; ++cb)
            bf[cb] = *(const bf16x8*)(hTb + ((wcol + (cb << 4) + m16) << 8) + (ks << 5) + (quad << 3));
        #pragma unroll
        for (int rb = 0; rb < 2; ++rb)
            #pragma unroll
            for (int cb = 0; cb < 2; ++cb)
                acc[rb][cb] = __builtin_amdgcn_mfma_f32_16x16x32_bf16(af[rb], bf[cb], acc[rb][cb], 0, 0, 0);
    }
    #pragma unroll
    for (int rb = 0; rb < 2; ++rb)
        #pragma unroll
        for (int cb = 0; cb < 2; ++cb)
            #pragma unroll
            for (int r = 0; r < 4; ++r)
                msgS[((rb << 4) + (quad << 2) + r) * 136 + wcol + (cb << 4) + m16] = f2bf(acc[rb][cb][r]);
    __syncthreads();   // covers h-half staging too

    // ---- a = msg @ Wa + ba ----
    #pragma unroll
    for (int rb = 0; rb < 2; ++rb)
        #pragma unroll
        for (int cb = 0; cb < 2; ++cb) acc[rb][cb] = (f32x4){0.f, 0.f, 0.f, 0.f};
    #pragma unroll
    for (int ks = 0; ks < 4; ++ks) {
        bf16x8 af[2], bf[2];
        #pragma unroll
        for (int rb = 0; rb < 2; ++rb)
            af[rb] = *(const bf16x8*)(msgS + ((rb << 4) + m16) * 136 + (ks << 5) + (quad << 3));
        #pragma unroll
        for (int cb = 0; cb < 2; ++cb)
            bf[cb] = *(const bf16x8*)(WaT + ((wcol + (cb << 4) + m16) << 7) + (ks << 5) + (quad << 3));
        #pragma unroll
        for (int rb = 0; rb < 2; ++rb)
            #pragma unroll
            for (int cb = 0; cb < 2; ++cb)
                acc[rb][cb] = __builtin_amdgcn_mfma_f32_16x16x32_bf16(af[rb], bf[cb], acc[rb][cb], 0, 0, 0);
    }
    {
        float bav[2];
        #pragma unroll
        for (int cb = 0; cb < 2; ++cb) bav[cb] = ba[wcol + (cb << 4) + m16];
        #pragma unroll
        for (int rb = 0; rb < 2; ++rb)
            #pragma unroll
            for (int cb = 0; cb < 2; ++cb)
                #pragma unroll
                for (int r = 0; r < 4; ++r)
                    ahS[((rb << 4) + (quad << 2) + r) * 264 + wcol + (cb << 4) + m16] =
                        f2bf(acc[rb][cb][r] + bav[cb]);
    }
    __syncthreads();

    // h_old (for r*h and final update): uint2 = 4 consecutive n at fixed col
    float hv[2][2][4];
    #pragma unroll
    for (int rb = 0; rb < 2; ++rb)
        #pragma unroll
        for (int cb = 0; cb < 2; ++cb) {
            int col = wcol + (cb << 4) + m16;
            uint2 u = *(const uint2*)(hTb + ((size_t)col << 8) + n0 + (rb << 4) + (quad << 2));
            hv[rb][cb][0] = bf2f((unsigned short)(u.x & 0xffff));
            hv[rb][cb][1] = bf2f((unsigned short)(u.x >> 16));
            hv[rb][cb][2] = bf2f((unsigned short)(u.y & 0xffff));
            hv[rb][cb][3] = bf2f((unsigned short)(u.y >> 16));
        }

    // ---- r and z ----
    f32x4 racc[2][2], zacc[2][2];
    #pragma unroll
    for (int rb = 0; rb < 2; ++rb)
        #pragma unroll
        for (int cb = 0; cb < 2; ++cb) {
            racc[rb][cb] = (f32x4){0.f, 0.f, 0.f, 0.f};
            zacc[rb][cb] = (f32x4){0.f, 0.f, 0.f, 0.f};
        }
    #pragma unroll 2
    for (int ks = 0; ks < 8; ++ks) {
        bf16x8 af[2], bfr[2], bfz[2];
        #pragma unroll
        for (int rb = 0; rb < 2; ++rb)
            af[rb] = *(const bf16x8*)(ahS + ((rb << 4) + m16) * 264 + (ks << 5) + (quad << 3));
        #pragma unroll
        for (int cb = 0; cb < 2; ++cb) {
            int dout = wcol + (cb << 4) + m16;
            bfr[cb] = *(const bf16x8*)(WrT + (dout << 8) + (ks << 5) + (quad << 3));
            bfz[cb] = *(const bf16x8*)(WzT + (dout << 8) + (ks << 5) + (quad << 3));
        }
        #pragma unroll
        for (int rb = 0; rb < 2; ++rb)
            #pragma unroll
            for (int cb = 0; cb < 2; ++cb) {
                racc[rb][cb] = __builtin_amdgcn_mfma_f32_16x16x32_bf16(af[rb], bfr[cb], racc[rb][cb], 0, 0, 0);
                zacc[rb][cb] = __builtin_amdgcn_mfma_f32_16x16x32_bf16(af[rb], bfz[cb], zacc[rb][cb], 0, 0, 0);
            }
    }
    float zv[2][2][4];
    {
        float brv[2], bzv[2];
        #pragma unroll
        for (int cb = 0; cb < 2; ++cb) {
            brv[cb] = br[wcol + (cb << 4) + m16];
            bzv[cb] = bz[wcol + (cb << 4) + m16];
        }
        #pragma unroll
        for (int rb = 0; rb < 2; ++rb)
            #pragma unroll
            for (int cb = 0; cb < 2; ++cb)
                #pragma unroll
                for (int r = 0; r < 4; ++r) {
                    racc[rb][cb][r] = sigmoidf_(racc[rb][cb][r] + brv[cb]);
                    zv[rb][cb][r]  = sigmoidf_(zacc[rb][cb][r] + bzv[cb]);
                }
    }
    __syncthreads();   // all ahS reads done -> safe to overwrite h-half

    #pragma unroll
    for (int rb = 0; rb < 2; ++rb)
        #pragma unroll
        for (int cb = 0; cb < 2; ++cb)
            #pragma unroll
            for (int r = 0; r < 4; ++r)
                ahS[((rb << 4) + (quad << 2) + r) * 264 + 128 + wcol + (cb << 4) + m16] =
                    f2bf(racc[rb][cb][r] * hv[rb][cb][r]);
    __syncthreads();

    // ---- h_tilde ----
    #pragma unroll
    for (int rb = 0; rb < 2; ++rb)
        #pragma unroll
        for (int cb = 0; cb < 2; ++cb) acc[rb][cb] = (f32x4){0.f, 0.f, 0.f, 0.f};
    #pragma unroll 2
    for (int ks = 0; ks < 8; ++ks) {
        bf16x8 af[2], bf[2];
        #pragma unroll
        for (int rb = 0; rb < 2; ++rb)
            af[rb] = *(const bf16x8*)(ahS + ((rb << 4) + m16) * 264 + (ks << 5) + (quad << 3));
        #pragma unroll
        for (int cb = 0; cb < 2; ++cb)
            bf[cb] = *(const bf16x8*)(WhT + ((wcol + (cb << 4) + m16) << 8) + (ks << 5) + (quad << 3));
        #pragma unroll
        for (int rb = 0; rb < 2; ++rb)
            #pragma unroll
            for (int cb = 0; cb < 2; ++cb)
                acc[rb][cb] = __builtin_amdgcn_mfma_f32_16x16x32_bf16(af[rb], bf[cb], acc[rb][cb], 0, 0, 0);
    }

    // ---- update + writes (hT only) ----
    {
        float bhv[2];
        #pragma unroll
        for (int cb = 0; cb < 2; ++cb) bhv[cb] = bh[wcol + (cb << 4) + m16];
        #pragma unroll
        for (int rb = 0; rb < 2; ++rb)
            #pragma unroll
            for (int cb = 0; cb < 2; ++cb) {
                int col = wcol + (cb << 4) + m16;
                unsigned short pk[4];
                #pragma unroll
                for (int r = 0; r < 4; ++r) {
                    float ht = tanhf_(acc[rb][cb][r] + bhv[cb]);
                    float hn = hv[rb][cb][r] + zv[rb][cb][r] * (ht - hv[rb][cb][r]);
                    pk[r] = f2bf(hn);
                }
                uint2 p;
                p.x = pack2(pk[0], pk[1]); p.y = pack2(pk[2], pk[3]);
                *(uint2*)(hT_o + ((size_t)(b * 128 + col) << 8) + n0 + (rb << 4) + (quad << 2)) = p;
            }
    }
}

// ---------------------------------------------------------------------------
// fc: logits[b,c] = sum over col-major h (hT1, b slice) + bfc. grid = 512.
// ---------------------------------------------------------------------------
__global__ __launch_bounds__(256) void k_fc(const unsigned short* __restrict__ hT,
                                            const float* __restrict__ Wfc,
                                            const float* __restrict__ bfc,
                                            float* __restrict__ out) {
    int bid = blockIdx.x;
    int b = bid >> 4, part = bid & 15;
    int tid = threadIdx.x;
    const unsigned short* hp = hT + ((size_t)b << 15);
    int i = part * 2048 + tid * 8;       // linear col-major: i = d*256 + n
    int d = i >> 8, n = i & 255;
    uint4 hu = *(const uint4*)(hp + i);
    unsigned short hs[8];
    hs[0] = hu.x & 0xffff; hs[1] = hu.x >> 16;
    hs[2] = hu.y & 0xffff; hs[3] = hu.y >> 16;
    hs[4] = hu.z & 0xffff; hs[5] = hu.z >> 16;
    hs[6] = hu.w & 0xffff; hs[7] = hu.w >> 16;
    float a0 = 0.f, a1 = 0.f;
    #pragma unroll
    for (int k = 0; k < 8; ++k) {
        float v = bf2f(hs[k]);
        const float2 w = *(const float2*)(Wfc + ((size_t)(n + k) * 128 + d) * 2);
        a0 = fmaf(v, w.x, a0);
        a1 = fmaf(v, w.y, a1);
    }
    int wave = tid >> 6, lane = tid & 63;
    #pragma unroll
    for (int off = 32; off; off >>= 1) {
        a0 += __shfl_down(a0, off, 64);
        a1 += __shfl_down(a1, off, 64);
    }
    __shared__ float r0[4], r1[4];
    if (lane == 0) { r0[wave] = a0; r1[wave] = a1; }
    __syncthreads();
    if (tid == 0) {
        float s0 = r0[0] + r0[1] + r0[2] + r0[3];
        float s1 = r1[0] + r1[1] + r1[2] + r1[3];
        if (part == 0) { s0 += bfc[0]; s1 += bfc[1]; }
        atomicAdd(&out[b * 2 + 0], s0);
        atomicAdd(&out[b * 2 + 1], s1);
    }
}

// ---------------------------------------------------------------------------
extern "C" void kernel_launch(void* const* d_in, const int* in_sizes, int n_in,
                              void* d_out, int out_size, void* d_ws, size_t ws_size,
                              hipStream_t stream) {
    const float* x_all    = (const float*)d_in[0];
    const float* supports = (const float*)d_in[1];
    const float* Wgl = (const float*)d_in[2];
    const float* Wa  = (const float*)d_in[3];
    const float* ba  = (const float*)d_in[4];
    const float* Wr  = (const float*)d_in[5];
    const float* br  = (const float*)d_in[6];
    const float* Wz  = (const float*)d_in[7];
    const float* bz  = (const float*)d_in[8];
    const float* Wh  = (const float*)d_in[9];
    const float* bh  = (const float*)d_in[10];
    const float* Wfc = (const float*)d_in[11];
    const float* bfc = (const float*)d_in[12];
    float* out = (float*)d_out;

    char* p = (char*)d_ws;
    auto alloc = [&](size_t bytes) { char* r = p; p += (bytes + 255) & ~(size_t)255; return r; };

    unsigned short* AttA = (unsigned short*)alloc((size_t)TT * BB * NN * NN * 2);  // 64 MB
    unsigned short* xh   = (unsigned short*)alloc((size_t)TT * BB * NN * DD * 2);  // 32 MB (f16)
    unsigned* invnH      = (unsigned*)alloc((size_t)TT * BB * 16 * NN * 4);        // 8 MB (dup f16)
    unsigned short* Afin = (unsigned short*)alloc((size_t)BB * NN * NN * 2);       // 4 MB
    unsigned short* hT0  = (unsigned short*)alloc((size_t)BB * DD * NN * 2);       // 2 MB
    unsigned short* hT1  = (unsigned short*)alloc((size_t)BB * DD * NN * 2);       // 2 MB
    unsigned short* WaT  = (unsigned short*)alloc(128 * 128 * 2);
    unsigned short* WrT  = (unsigned short*)alloc(256 * 128 * 2);
    unsigned short* WzT  = (unsigned short*)alloc(256 * 128 * 2);
    unsigned short* WhT  = (unsigned short*)alloc(256 * 128 * 2);
    unsigned* wsqH       = (unsigned*)alloc(16 * 64 * 4);                          // 4 KB
    // total ~112.5 MB

    k_wprep<<<128, 256, 0, stream>>>(Wa, Wr, Wz, Wh, Wgl, WaT, WrT, WzT, WhT, wsqH);
    k_norms<<<TT * BB * 16, 256, 0, stream>>>(x_all, Wgl, xh, invnH);

    // attention path: all 16 t in one dispatch
    k_gram2<<<4 * TT * BB, 256, 0, stream>>>(xh, wsqH, invnH, AttA);
    k_scanlast<<<2048, 256, 0, stream>>>(supports, AttA, Afin);

    // GRU path: ONLY t=15 is live (reference uses outs[-1] only)
    const float* x15 = x_all + (size_t)15 * BB * NN * DD;
    k_hTinit<<<BB * 32, 256, 0, stream>>>(x15, hT0);

    const unsigned short* hT_in = hT0;
    for (int s = 0; s < NSTEPS; ++s) {
        unsigned short* hTo = (s & 1) ? hT0 : hT1;
        k_step<<<8 * BB, 256, 0, stream>>>(Afin, hT_in,
                                           WaT, ba, WrT, br, WzT, bz, WhT, bh,
                                           hTo);
        hT_in = hTo;
    }
    // after 5 steps (s=4) final h is in hT1
    hipMemsetAsync(d_out, 0, (size_t)out_size * sizeof(float), stream);
    k_fc<<<BB * 16, 256, 0, stream>>>(hT1, Wfc, bfc, out);
}

// Round 7
// 363.603 us; speedup vs baseline: 1.3374x; 1.0231x over previous
//
#include <hip/hip_runtime.h>
#include <math.h>

#define TT 16
#define BB 32
#define NN 256
#define DD 128
#define NSTEPS 5
#define SKIPF 0.3f
#define EPSF 1e-8f

// R7: only outs[-1] is live -> GRU for t<15 is dead code.
// R9: V eliminated; gram computed from staged low-precision x.
// R10: register-resident gram2. R11: LDS tables (issue-saturated at 91%).
// R12: f16 packed-math gram (VALU 62 + MFMA 41 = 103% -> pure inst-count).
// R13/R14: container failures -> bisected in R15: kernel fine, infra fault
//   (R13: 406s npz push; R14: failed before any kernel ran).
// R15: 64x64 gram tiles PASSED: 372us, gram2 145us (MfmaUtil 42, VALU 52).
// R16 (this round): re-add the audited k_prep (MFMA norms + f16 convert,
//   the other half of R13). k_norms' 64 ds_read/thread loop (~45us) ->
//   memory-bound ~21us (64MB read + 40MB write).

typedef __attribute__((ext_vector_type(8))) short bf16x8;
typedef __attribute__((ext_vector_type(4))) float f32x4;
typedef __attribute__((ext_vector_type(8))) _Float16 half8;
typedef __attribute__((ext_vector_type(2))) _Float16 h2;

__device__ __forceinline__ unsigned short f2bf(float f) {
    union { float f; unsigned u; } v; v.f = f;
    unsigned r = (v.u + 0x7FFF + ((v.u >> 16) & 1)) >> 16;
    return (unsigned short)r;
}
__device__ __forceinline__ float bf2f(unsigned short u) {
    union { unsigned u; float f; } v; v.u = ((unsigned)u) << 16; return v.f;
}
__device__ __forceinline__ unsigned pack2(unsigned short a, unsigned short b) {
    return (unsigned)a | ((unsigned)b << 16);
}
// packed f32->f16 convert (RTZ), 1 inst for 2 elems
__device__ __forceinline__ unsigned pkrtz(float a, float b) {
    unsigned r;
    asm("v_cvt_pkrtz_f16_f32 %0, %1, %2" : "=v"(r) : "v"(a), "v"(b));
    return r;
}
__device__ __forceinline__ h2 u2h(unsigned u) {
    union { unsigned u; h2 h; } v; v.u = u; return v.h;
}
__device__ __forceinline__ float sigmoidf_(float x) {
    return 1.0f / (1.0f + __expf(-x));
}
__device__ __forceinline__ float tanhf_(float x) {
    return 1.0f - 2.0f / (__expf(2.0f * x) + 1.0f);
}

// ---------------------------------------------------------------------------
// prep: per tb block (512 blocks, 256 thr):
//   xh = f16(x)  (32 MB total, coalesced)
//   invnH[tb][h][n] = dup-f16(1/(sqrt(sum_d x^2 w^2)+eps)) via MFMA:
//     A = x^2 (f16, LDS, XOR-16 swizzle), B = w^2 (f16, from L1/global).
// MFMA layout: A lane m16 = row n, B lane m16 = col h, D (row=quad*4+r -> n,
// col=m16 -> h) matches invnH[tb][h][n] write. Swizzle same involution on
// write and read.
// ---------------------------------------------------------------------------
__global__ __launch_bounds__(256) void k_prep(const float* __restrict__ x,
                                              const unsigned* __restrict__ wsqH,
                                              unsigned short* __restrict__ xh,
                                              unsigned* __restrict__ invnH) {
    int tb = blockIdx.x;
    int tid = threadIdx.x;
    int wave = tid >> 6, lane = tid & 63;
    int m16 = lane & 15, quad = lane >> 4;

    __shared__ unsigned short xsq[256 * 128];   // 64 KB f16, XOR-16 by row&7

    const float* xb = x + ((size_t)tb << 15);
    unsigned short* xhb = xh + ((size_t)tb << 15);

    // stage: 32768 floats, 8/thread/iter, coalesced
    #pragma unroll
    for (int it = 0; it < 16; ++it) {
        int flat = (it << 11) + (tid << 3);
        float4 a = *(const float4*)(xb + flat);
        float4 b = *(const float4*)(xb + flat + 4);
        uint4 o;
        o.x = pkrtz(a.x, a.y); o.y = pkrtz(a.z, a.w);
        o.z = pkrtz(b.x, b.y); o.w = pkrtz(b.z, b.w);
        *(uint4*)(xhb + flat) = o;
        uint4 q;
        q.x = pkrtz(a.x * a.x, a.y * a.y); q.y = pkrtz(a.z * a.z, a.w * a.w);
        q.z = pkrtz(b.x * b.x, b.y * b.y); q.w = pkrtz(b.z * b.z, b.w * b.w);
        int row = flat >> 7;
        int byteoff = (flat << 1) ^ ((row & 7) << 4);
        *(uint4*)((char*)xsq + byteoff) = q;
    }
    __syncthreads();

    // B-frags: w^2 rows (h = m16) from global (4 KB, L1-resident)
    half8 wf[4];
    #pragma unroll
    for (int ks = 0; ks < 4; ++ks)
        wf[ks] = *(const half8*)((const unsigned short*)wsqH + (m16 << 7) + (ks << 5) + (quad << 3));

    #pragma unroll
    for (int sub = 0; sub < 4; ++sub) {
        int rbase = (wave << 6) + (sub << 4);
        f32x4 acc = (f32x4){0.f, 0.f, 0.f, 0.f};
        #pragma unroll
        for (int ks = 0; ks < 4; ++ks) {
            int row = rbase + m16;
            int byteoff = ((row << 8) + (ks << 6) + (quad << 4)) ^ ((row & 7) << 4);
            half8 af = *(const half8*)((const char*)xsq + byteoff);
            acc = __builtin_amdgcn_mfma_f32_16x16x32_f16(af, wf[ks], acc, 0, 0, 0);
        }
        unsigned out[4];
        #pragma unroll
        for (int r = 0; r < 4; ++r) {
            float inv = 1.0f / (sqrtf(acc[r]) + EPSF);
            out[r] = pkrtz(inv, inv);
        }
        int n = rbase + (quad << 2);
        *(uint4*)(invnH + ((size_t)tb << 12) + (m16 << 8) + n) = *(uint4*)out;
    }
}

// ---------------------------------------------------------------------------
// gram2 (f16 packed, 64x64 wave tiles) — VERIFIED R15:
//   attn_t = 0.7*rownorm(relu(sum_h D_h X W2_h X^T D_h)).
// grid = 4 rg x 512 tb = 2048 blocks, 256 threads, LDS 21 KB.
// ---------------------------------------------------------------------------
__global__ __launch_bounds__(256, 2) void k_gram2(const unsigned short* __restrict__ xhp,
                                                  const unsigned* __restrict__ wsqH,
                                                  const unsigned* __restrict__ invnH,
                                                  unsigned short* __restrict__ attn) {
    int bid = blockIdx.x;
    int tb = bid & 511;
    int rg = bid >> 9;                  // 0..3
    int n0 = rg << 6;
    int tid = threadIdx.x;
    int wave = tid >> 6, lane = tid & 63;
    int m16 = lane & 15, quad = lane >> 4;
    int wcol = wave << 6;

    __shared__ unsigned wS[16 * 64];     // 4 KB: w^2 packed f16 pairs [h][d/2]
    __shared__ unsigned ivS[16 * 256];   // 16 KB: invn dup-f16 [h][n]
    __shared__ float rsum[4][64];        // 1 KB

    const unsigned short* Xb = xhp + ((size_t)tb << 15);

    // ---- stage tables ----
    {
        uint4 v = *(const uint4*)(wsqH + (tid << 2));
        *(uint4*)(wS + (tid << 2)) = v;
    }
    {
        const unsigned* src = invnH + ((size_t)tb << 12);
        #pragma unroll
        for (int hh = 0; hh < 16; ++hh)
            ivS[(hh << 8) + tid] = src[(hh << 8) + tid];
    }

    // ---- resident raw fragments (packed f16) ----
    half8 Bf[4][4];                     // [ks][cb] = 64 VGPR (wave's 64 cols)
    #pragma unroll
    for (int ks = 0; ks < 4; ++ks)
        #pragma unroll
        for (int cb = 0; cb < 4; ++cb)
            Bf[ks][cb] = *(const half8*)(Xb + ((wcol + (cb << 4) + m16) << 7) + (ks << 5) + (quad << 3));

    half8 Af[4][4];                     // [rb][ks] = 64 VGPR (block's 64 rows)
    #pragma unroll
    for (int rb = 0; rb < 4; ++rb)
        #pragma unroll
        for (int ks = 0; ks < 4; ++ks)
            Af[rb][ks] = *(const half8*)(Xb + ((n0 + (rb << 4) + m16) << 7) + (ks << 5) + (quad << 3));

    f32x4 att[4][4];
    #pragma unroll
    for (int rb = 0; rb < 4; ++rb)
        #pragma unroll
        for (int cb = 0; cb < 4; ++cb) att[rb][cb] = (f32x4){0.f, 0.f, 0.f, 0.f};

    __syncthreads();   // tables staged

    union H8 { half8 v; h2 p[4]; };

    #pragma unroll 1
    for (int h = 0; h < 16; ++h) {
        const unsigned* ivh = ivS + (h << 8);
        h2 ivr[4], ivc[4];
        #pragma unroll
        for (int rb = 0; rb < 4; ++rb) ivr[rb] = u2h(ivh[n0 + (rb << 4) + m16]);
        #pragma unroll
        for (int cb = 0; cb < 4; ++cb) ivc[cb] = u2h(ivh[wcol + (cb << 4) + m16]);

        #pragma unroll
        for (int ks = 0; ks < 4; ++ks) {
            uint4 wu = *(const uint4*)(wS + (h << 6) + (ks << 4) + (quad << 2));
            h2 w0 = u2h(wu.x), w1 = u2h(wu.y), w2 = u2h(wu.z), w3 = u2h(wu.w);

            H8 afr[4];
            #pragma unroll
            for (int rb = 0; rb < 4; ++rb) {
                H8 a; a.v = Af[rb][ks];
                h2 s = ivr[rb];
                afr[rb].p[0] = a.p[0] * (w0 * s);
                afr[rb].p[1] = a.p[1] * (w1 * s);
                afr[rb].p[2] = a.p[2] * (w2 * s);
                afr[rb].p[3] = a.p[3] * (w3 * s);
            }
            #pragma unroll
            for (int cb = 0; cb < 4; ++cb) {
                H8 b; b.v = Bf[ks][cb];
                H8 bf;
                bf.p[0] = b.p[0] * ivc[cb];
                bf.p[1] = b.p[1] * ivc[cb];
                bf.p[2] = b.p[2] * ivc[cb];
                bf.p[3] = b.p[3] * ivc[cb];
                #pragma unroll
                for (int rb = 0; rb < 4; ++rb)
                    att[rb][cb] = __builtin_amdgcn_mfma_f32_16x16x32_f16(afr[rb].v, bf.v, att[rb][cb], 0, 0, 0);
            }
        }
    }

    // relu + rowsum + normalize (x0.7) -> bf16 attn  (relu(S)/16 trick: +16eps)
    float rs[4][4];
    #pragma unroll
    for (int rb = 0; rb < 4; ++rb)
        #pragma unroll
        for (int r = 0; r < 4; ++r) {
            float s = 0.f;
            #pragma unroll
            for (int cb = 0; cb < 4; ++cb) {
                float v = fmaxf(att[rb][cb][r], 0.0f);
                att[rb][cb][r] = v;
                s += v;
            }
            rs[rb][r] = s;
        }
    #pragma unroll
    for (int m = 1; m < 16; m <<= 1)
        #pragma unroll
        for (int rb = 0; rb < 4; ++rb)
            #pragma unroll
            for (int r = 0; r < 4; ++r)
                rs[rb][r] += __shfl_xor(rs[rb][r], m, 64);
    if (m16 == 0) {
        #pragma unroll
        for (int rb = 0; rb < 4; ++rb)
            #pragma unroll
            for (int r = 0; r < 4; ++r)
                rsum[wave][(rb << 4) + (quad << 2) + r] = rs[rb][r];
    }
    __syncthreads();

    unsigned short* outb = attn + ((size_t)tb << 16);
    #pragma unroll
    for (int rb = 0; rb < 4; ++rb) {
        #pragma unroll
        for (int r = 0; r < 4; ++r) {
            int row = (rb << 4) + (quad << 2) + r;
            float tot = rsum[0][row] + rsum[1][row] + rsum[2][row] + rsum[3][row];
            float inv = (1.0f - SKIPF) / (tot + 16.0f * EPSF);
            #pragma unroll
            for (int cb = 0; cb < 4; ++cb) {
                int col = wcol + (cb << 4) + m16;
                outb[((size_t)(n0 + row) << 8) + col] = f2bf(att[rb][cb][r] * inv);
            }
        }
    }
}

// ---------------------------------------------------------------------------
// scanlast: a=supports; a=0.3a+attn_t; write only A_15 (bf16). grid 2048x256.
// ---------------------------------------------------------------------------
__global__ __launch_bounds__(256) void k_scanlast(const float* __restrict__ supports,
                                                  const unsigned short* __restrict__ AttA,
                                                  unsigned short* __restrict__ Afin) {
    size_t flat = ((size_t)blockIdx.x * 256 + threadIdx.x) * 4;
    float4 s4 = *(const float4*)(supports + flat);
    float a0 = s4.x, a1 = s4.y, a2 = s4.z, a3 = s4.w;
    #pragma unroll
    for (int t = 0; t < TT; ++t) {
        const unsigned short* p = AttA + ((size_t)t << 21) + flat;
        uint2 u = *(const uint2*)p;
        a0 = SKIPF * a0 + bf2f((unsigned short)(u.x & 0xffff));
        a1 = SKIPF * a1 + bf2f((unsigned short)(u.x >> 16));
        a2 = SKIPF * a2 + bf2f((unsigned short)(u.y & 0xffff));
        a3 = SKIPF * a3 + bf2f((unsigned short)(u.y >> 16));
    }
    uint2 o;
    o.x = pack2(f2bf(a0), f2bf(a1));
    o.y = pack2(f2bf(a2), f2bf(a3));
    *(uint2*)(Afin + flat) = o;
}

// NOTE: AttA is indexed [tb][n][m] with tb = t*32+b; scanlast's flat index
// covers b,n,m for fixed t via offset t<<21 — consistent with gram2's tb.

// ---------------------------------------------------------------------------
// hTinit: hT0[b][d][n] = bf16(x15[b][n][d]) for b=0..31. grid 32*32 blocks.
// ---------------------------------------------------------------------------
__global__ __launch_bounds__(256) void k_hTinit(const float* __restrict__ x15,
                                                unsigned short* __restrict__ hT) {
    int bid = blockIdx.x;
    int b = bid >> 5; int r = bid & 31; int d0 = (r >> 3) << 5; int n0 = (r & 7) << 5;
    __shared__ float tl[32][33];
    int tid = threadIdx.x;
    int i = tid >> 5, j = tid & 31;
    #pragma unroll
    for (int s = 0; s < 4; ++s) {
        int nl = (s << 3) + i;
        tl[nl][j] = x15[((size_t)(b * 256 + n0 + nl) << 7) + d0 + j];
    }
    __syncthreads();
    #pragma unroll
    for (int s = 0; s < 4; ++s) {
        int dd = (s << 3) + i;
        hT[((size_t)(b * 128 + d0 + dd) << 8) + n0 + j] = f2bf(tl[j][dd]);
    }
}

// ---------------------------------------------------------------------------
// wprep: bf16-transposed weights WT[dout][k] + packed-f16 w^2 table
// ---------------------------------------------------------------------------
__global__ __launch_bounds__(256) void k_wprep(const float* __restrict__ Wa,
                                               const float* __restrict__ Wr,
                                               const float* __restrict__ Wz,
                                               const float* __restrict__ Wh,
                                               const float* __restrict__ Wgl,
                                               unsigned short* __restrict__ WaT,
                                               unsigned short* __restrict__ WrT,
                                               unsigned short* __restrict__ WzT,
                                               unsigned short* __restrict__ WhT,
                                               unsigned* __restrict__ wsqH) {
    int idx = blockIdx.x * 256 + threadIdx.x;     // 0..32767
    if (idx < 16384) {
        int dout = idx >> 7, din = idx & 127;
        WaT[idx] = f2bf(Wa[(din << 7) + dout]);
    }
    if (idx < 1024) {
        // wsqH[h][j] = packed f16 (w[2j]^2, w[2j+1]^2)
        int h = idx >> 6, j = idx & 63;
        float w0 = Wgl[(h << 7) + (j << 1)];
        float w1 = Wgl[(h << 7) + (j << 1) + 1];
        wsqH[idx] = pkrtz(w0 * w0, w1 * w1);
    }
    {
        int dout = idx >> 8, dk = idx & 255;
        WrT[idx] = f2bf(Wr[(dk << 7) + dout]);
        WzT[idx] = f2bf(Wz[(dk << 7) + dout]);
        WhT[idx] = f2bf(Wh[(dk << 7) + dout]);
    }
}

// ---------------------------------------------------------------------------
// step: fused GGNN/GRU step for t=15 only: b = 0..31, 32-row tiles.
// h state in hT (bf16, [b][d][n]). grid = 8 rg x 32 b = 256 blocks.
// ---------------------------------------------------------------------------
__global__ __launch_bounds__(256) void k_step(
    const unsigned short* __restrict__ Afin,
    const unsigned short* __restrict__ hT,
    const unsigned short* __restrict__ WaT, const float* __restrict__ ba,
    const unsigned short* __restrict__ WrT, const float* __restrict__ br,
    const unsigned short* __restrict__ WzT, const float* __restrict__ bz,
    const unsigned short* __restrict__ WhT, const float* __restrict__ bh,
    unsigned short* __restrict__ hT_o) {

    int bid = blockIdx.x;
    int b = bid & 31, rg = bid >> 5;
    int n0 = rg << 5;
    int tid = threadIdx.x;
    int wave = tid >> 6, lane = tid & 63;
    int m16 = lane & 15, quad = lane >> 4;
    int wcol = wave << 5;

    __shared__ unsigned short msgS[32 * 136];
    __shared__ unsigned short ahS[32 * 264];   // k 0..127 = a, 128..255 = h (later r*h)

    const unsigned short* hTb = hT + ((size_t)b << 15);

    // stage h-half of ahS from hT (transpose: ahS[row][128+d] = hT[d][n0+row])
    #pragma unroll
    for (int j = 0; j < 16; ++j) {
        int idx = (j << 8) + tid;            // 0..4095
        int d = idx >> 5, row = idx & 31;
        ahS[row * 264 + 128 + d] = hTb[((size_t)d << 8) + n0 + row];
    }

    // ---- bmm: msg = A_tile @ h  (K=256) ----
    f32x4 acc[2][2];
    #pragma unroll
    for (int rb = 0; rb < 2; ++rb)
        #pragma unroll
        for (int cb = 0; cb < 2; ++cb) acc[rb][cb] = (f32x4){0.f, 0.f, 0.f, 0.f};

    const unsigned short* Ab = Afin + ((size_t)b << 16) + ((size_t)n0 << 8);
    #pragma unroll 2
    for (int ks = 0; ks < 8; ++ks) {
        bf16x8 af[2], bf[2];
        #pragma unroll
        for (int rb = 0; rb < 2; ++rb)
            af[rb] = *(const bf16x8*)(Ab + (((rb << 4) + m16) << 8) + (ks << 5) + (quad << 3));
        #pragma unroll
        for (int cb = 0; cb < 2; ++cb)
            bf[cb] = *(const bf16x8*)(hTb + ((wcol + (cb << 4) + m16) << 8) + (ks << 5) + (quad << 3));
        #pragma unroll
        for (int rb = 0; rb < 2; ++rb)
            #pragma unroll
            for (int cb = 0; cb < 2; ++cb)
                acc[rb][cb] = __builtin_amdgcn_mfma_f32_16x16x32_bf16(af[rb], bf[cb], acc[rb][cb], 0, 0, 0);
    }
    #pragma unroll
    for (int rb = 0; rb < 2; ++rb)
        #pragma unroll
        for (int cb = 0; cb < 2; ++cb)
            #pragma unroll
            for (int r = 0; r < 4; ++r)
                msgS[((rb << 4) + (quad << 2) + r) * 136 + wcol + (cb << 4) + m16] = f2bf(acc[rb][cb][r]);
    __syncthreads();   // covers h-half staging too

    // ---- a = msg @ Wa + ba ----
    #pragma unroll
    for (int rb = 0; rb < 2; ++rb)
        #pragma unroll
        for (int cb = 0; cb < 2; ++cb) acc[rb][cb] = (f32x4){0.f, 0.f, 0.f, 0.f};
    #pragma unroll
    for (int ks = 0; ks < 4; ++ks) {
        bf16x8 af[2], bf[2];
        #pragma unroll
        for (int rb = 0; rb < 2; ++rb)
            af[rb] = *(const bf16x8*)(msgS + ((rb << 4) + m16) * 136 + (ks << 5) + (quad << 3));
        #pragma unroll
        for (int cb = 0; cb < 2; ++cb)
            bf[cb] = *(const bf16x8*)(WaT + ((wcol + (cb << 4) + m16) << 7) + (ks << 5) + (quad << 3));
        #pragma unroll
        for (int rb = 0; rb < 2; ++rb)
            #pragma unroll
            for (int cb = 0; cb < 2; ++cb)
                acc[rb][cb] = __builtin_amdgcn_mfma_f32_16x16x32_bf16(af[rb], bf[cb], acc[rb][cb], 0, 0, 0);
    }
    {
        float bav[2];
        #pragma unroll
        for (int cb = 0; cb < 2; ++cb) bav[cb] = ba[wcol + (cb << 4) + m16];
        #pragma unroll
        for (int rb = 0; rb < 2; ++rb)
            #pragma unroll
            for (int cb = 0; cb < 2; ++cb)
                #pragma unroll
                for (int r = 0; r < 4; ++r)
                    ahS[((rb << 4) + (quad << 2) + r) * 264 + wcol + (cb << 4) + m16] =
                        f2bf(acc[rb][cb][r] + bav[cb]);
    }
    __syncthreads();

    // h_old (for r*h and final update): uint2 = 4 consecutive n at fixed col
    float hv[2][2][4];
    #pragma unroll
    for (int rb = 0; rb < 2; ++rb)
        #pragma unroll
        for (int cb = 0; cb < 2; ++cb) {
            int col = wcol + (cb << 4) + m16;
            uint2 u = *(const uint2*)(hTb + ((size_t)col << 8) + n0 + (rb << 4) + (quad << 2));
            hv[rb][cb][0] = bf2f((unsigned short)(u.x & 0xffff));
            hv[rb][cb][1] = bf2f((unsigned short)(u.x >> 16));
            hv[rb][cb][2] = bf2f((unsigned short)(u.y & 0xffff));
            hv[rb][cb][3] = bf2f((unsigned short)(u.y >> 16));
        }

    // ---- r and z ----
    f32x4 racc[2][2], zacc[2][2];
    #pragma unroll
    for (int rb = 0; rb < 2; ++rb)
        #pragma unroll
        for (int cb = 0; cb < 2; ++cb) {
            racc[rb][cb] = (f32x4){0.f, 0.f, 0.f, 0.f};
            zacc[rb][cb] = (f32x4){0.f, 0.f, 0.f, 0.f};
        }
    #pragma unroll 2
    for (int ks = 0; ks < 8; ++ks) {
        bf16x8 af[2], bfr[2], bfz[2];
        #pragma unroll
        for (int rb = 0; rb < 2; ++rb)
            af[rb] = *(const bf16x8*)(ahS + ((rb << 4) + m16) * 264 + (ks << 5) + (quad << 3));
        #pragma unroll
        for (int cb = 0; cb < 2; ++cb) {
            int dout = wcol + (cb << 4) + m16;
            bfr[cb] = *(const bf16x8*)(WrT + (dout << 8) + (ks << 5) + (quad << 3));
            bfz[cb] = *(const bf16x8*)(WzT + (dout << 8) + (ks << 5) + (quad << 3));
        }
        #pragma unroll
        for (int rb = 0; rb < 2; ++rb)
            #pragma unroll
            for (int cb = 0; cb < 2; ++cb) {
                racc[rb][cb] = __builtin_amdgcn_mfma_f32_16x16x32_bf16(af[rb], bfr[cb], racc[rb][cb], 0, 0, 0);
                zacc[rb][cb] = __builtin_amdgcn_mfma_f32_16x16x32_bf16(af[rb], bfz[cb], zacc[rb][cb], 0, 0, 0);
            }
    }
    float zv[2][2][4];
    {
        float brv[2], bzv[2];
        #pragma unroll
        for (int cb = 0; cb < 2; ++cb) {
            brv[cb] = br[wcol + (cb << 4) + m16];
            bzv[cb] = bz[wcol + (cb << 4) + m16];
        }
        #pragma unroll
        for (int rb = 0; rb < 2; ++rb)
            #pragma unroll
            for (int cb = 0; cb < 2; ++cb)
                #pragma unroll
                for (int r = 0; r < 4; ++r) {
                    racc[rb][cb][r] = sigmoidf_(racc[rb][cb][r] + brv[cb]);
                    zv[rb][cb][r]  = sigmoidf_(zacc[rb][cb][r] + bzv[cb]);
                }
    }
    __syncthreads();   // all ahS reads done -> safe to overwrite h-half

    #pragma unroll
    for (int rb = 0; rb < 2; ++rb)
        #pragma unroll
        for (int cb = 0; cb < 2; ++cb)
            #pragma unroll
            for (int r = 0; r < 4; ++r)
                ahS[((rb << 4) + (quad << 2) + r) * 264 + 128 + wcol + (cb << 4) + m16] =
                    f2bf(racc[rb][cb][r] * hv[rb][cb][r]);
    __syncthreads();

    // ---- h_tilde ----
    #pragma unroll
    for (int rb = 0; rb < 2; ++rb)
        #pragma unroll
        for (int cb = 0; cb < 2; ++cb) acc[rb][cb] = (f32x4){0.f, 0.f, 0.f, 0.f};
    #pragma unroll 2
    for (int ks = 0; ks < 8; ++ks) {
        bf16x8 af[2], bf[2];
        #pragma unroll
        for (int rb = 0; rb < 2; ++rb)
            af[rb] = *(const bf16x8*)(ahS + ((rb << 4) + m16) * 264 + (ks << 5) + (quad << 3));
        #pragma unroll
        for (int cb = 0; cb < 2; ++cb)
            bf[cb] = *(const bf16x8*)(WhT + ((wcol + (cb << 4) + m16) << 8) + (ks << 5) + (quad << 3));
        #pragma unroll
        for (int rb = 0; rb < 2; ++rb)
            #pragma unroll
            for (int cb = 0; cb < 2; ++cb)
                acc[rb][cb] = __builtin_amdgcn_mfma_f32_16x16x32_bf16(af[rb], bf[cb], acc[rb][cb], 0, 0, 0);
    }

    // ---- update + writes (hT only) ----
    {
        float bhv[2];
        #pragma unroll
        for (int cb = 0; cb < 2; ++cb) bhv[cb] = bh[wcol + (cb << 4) + m16];
        #pragma unroll
        for (int rb = 0; rb < 2; ++rb)
            #pragma unroll
            for (int cb = 0; cb < 2; ++cb) {
                int col = wcol + (cb << 4) + m16;
                unsigned short pk[4];
                #pragma unroll
                for (int r = 0; r < 4; ++r) {
                    float ht = tanhf_(acc[rb][cb][r] + bhv[cb]);
                    float hn = hv[rb][cb][r] + zv[rb][cb][r] * (ht - hv[rb][cb][r]);
                    pk[r] = f2bf(hn);
                }
                uint2 p;
                p.x = pack2(pk[0], pk[1]); p.y = pack2(pk[2], pk[3]);
                *(uint2*)(hT_o + ((size_t)(b * 128 + col) << 8) + n0 + (rb << 4) + (quad << 2)) = p;
            }
    }
}

// ---------------------------------------------------------------------------
// fc: logits[b,c] = sum over col-major h (hT1, b slice) + bfc. grid = 512.
// ---------------------------------------------------------------------------
__global__ __launch_bounds__(256) void k_fc(const unsigned short* __restrict__ hT,
                                            const float* __restrict__ Wfc,
                                            const float* __restrict__ bfc,
                                            float* __restrict__ out) {
    int bid = blockIdx.x;
    int b = bid >> 4, part = bid & 15;
    int tid = threadIdx.x;
    const unsigned short* hp = hT + ((size_t)b << 15);
    int i = part * 2048 + tid * 8;       // linear col-major: i = d*256 + n
    int d = i >> 8, n = i & 255;
    uint4 hu = *(const uint4*)(hp + i);
    unsigned short hs[8];
    hs[0] = hu.x & 0xffff; hs[1] = hu.x >> 16;
    hs[2] = hu.y & 0xffff; hs[3] = hu.y >> 16;
    hs[4] = hu.z & 0xffff; hs[5] = hu.z >> 16;
    hs[6] = hu.w & 0xffff; hs[7] = hu.w >> 16;
    float a0 = 0.f, a1 = 0.f;
    #pragma unroll
    for (int k = 0; k < 8; ++k) {
        float v = bf2f(hs[k]);
        const float2 w = *(const float2*)(Wfc + ((size_t)(n + k) * 128 + d) * 2);
        a0 = fmaf(v, w.x, a0);
        a1 = fmaf(v, w.y, a1);
    }
    int wave = tid >> 6, lane = tid & 63;
    #pragma unroll
    for (int off = 32; off; off >>= 1) {
        a0 += __shfl_down(a0, off, 64);
        a1 += __shfl_down(a1, off, 64);
    }
    __shared__ float r0[4], r1[4];
    if (lane == 0) { r0[wave] = a0; r1[wave] = a1; }
    __syncthreads();
    if (tid == 0) {
        float s0 = r0[0] + r0[1] + r0[2] + r0[3];
        float s1 = r1[0] + r1[1] + r1[2] + r1[3];
        if (part == 0) { s0 += bfc[0]; s1 += bfc[1]; }
        atomicAdd(&out[b * 2 + 0], s0);
        atomicAdd(&out[b * 2 + 1], s1);
    }
}

// ---------------------------------------------------------------------------
extern "C" void kernel_launch(void* const* d_in, const int* in_sizes, int n_in,
                              void* d_out, int out_size, void* d_ws, size_t ws_size,
                              hipStream_t stream) {
    const float* x_all    = (const float*)d_in[0];
    const float* supports = (const float*)d_in[1];
    const float* Wgl = (const float*)d_in[2];
    const float* Wa  = (const float*)d_in[3];
    const float* ba  = (const float*)d_in[4];
    const float* Wr  = (const float*)d_in[5];
    const float* br  = (const float*)d_in[6];
    const float* Wz  = (const float*)d_in[7];
    const float* bz  = (const float*)d_in[8];
    const float* Wh  = (const float*)d_in[9];
    const float* bh  = (const float*)d_in[10];
    const float* Wfc = (const float*)d_in[11];
    const float* bfc = (const float*)d_in[12];
    float* out = (float*)d_out;

    char* p = (char*)d_ws;
    auto alloc = [&](size_t bytes) { char* r = p; p += (bytes + 255) & ~(size_t)255; return r; };

    unsigned short* AttA = (unsigned short*)alloc((size_t)TT * BB * NN * NN * 2);  // 64 MB
    unsigned short* xh   = (unsigned short*)alloc((size_t)TT * BB * NN * DD * 2);  // 32 MB (f16)
    unsigned* invnH      = (unsigned*)alloc((size_t)TT * BB * 16 * NN * 4);        // 8 MB (dup f16)
    unsigned short* Afin = (unsigned short*)alloc((size_t)BB * NN * NN * 2);       // 4 MB
    unsigned short* hT0  = (unsigned short*)alloc((size_t)BB * DD * NN * 2);       // 2 MB
    unsigned short* hT1  = (unsigned short*)alloc((size_t)BB * DD * NN * 2);       // 2 MB
    unsigned short* WaT  = (unsigned short*)alloc(128 * 128 * 2);
    unsigned short* WrT  = (unsigned short*)alloc(256 * 128 * 2);
    unsigned short* WzT  = (unsigned short*)alloc(256 * 128 * 2);
    unsigned short* WhT  = (unsigned short*)alloc(256 * 128 * 2);
    unsigned* wsqH       = (unsigned*)alloc(16 * 64 * 4);                          // 4 KB
    // total ~112.5 MB

    k_wprep<<<128, 256, 0, stream>>>(Wa, Wr, Wz, Wh, Wgl, WaT, WrT, WzT, WhT, wsqH);
    k_prep<<<TT * BB, 256, 0, stream>>>(x_all, wsqH, xh, invnH);

    // attention path: all 16 t in one dispatch
    k_gram2<<<4 * TT * BB, 256, 0, stream>>>(xh, wsqH, invnH, AttA);
    k_scanlast<<<2048, 256, 0, stream>>>(supports, AttA, Afin);

    // GRU path: ONLY t=15 is live (reference uses outs[-1] only)
    const float* x15 = x_all + (size_t)15 * BB * NN * DD;
    k_hTinit<<<BB * 32, 256, 0, stream>>>(x15, hT0);

    const unsigned short* hT_in = hT0;
    for (int s = 0; s < NSTEPS; ++s) {
        unsigned short* hTo = (s & 1) ? hT0 : hT1;
        k_step<<<8 * BB, 256, 0, stream>>>(Afin, hT_in,
                                           WaT, ba, WrT, br, WzT, bz, WhT, bh,
                                           hTo);
        hT_in = hTo;
    }
    // after 5 steps (s=4) final h is in hT1
    hipMemsetAsync(d_out, 0, (size_t)out_size * sizeof(float), stream);
    k_fc<<<BB * 16, 256, 0, stream>>>(hT1, Wfc, bfc, out);
}